// Round 7
// baseline (141.235 us; speedup 1.0000x reference)
//
#include <hip/hip_runtime.h>
#include <hip/hip_bf16.h>
#include <math.h>

#define NPIX 4096   // H*W
#define CIN  512
#define DD   64
#define BB   4
#define NCHUNK 8    // KV chunks for flash-decode split (chunk = 512)

using f32x4  = __attribute__((ext_vector_type(4))) float;
using bf16x8 = __attribute__((ext_vector_type(8))) short;
using u16x4  = __attribute__((ext_vector_type(4))) unsigned short;

__device__ __forceinline__ unsigned short f2bf(float f){
    union { __hip_bfloat16 h; unsigned short u; } v;
    v.h = __float2bfloat16(f);            // RNE
    return v.u;
}

__device__ __forceinline__ unsigned pk2(float a, float b){
    union { __hip_bfloat162 h; unsigned u; } v;
    v.h = __float22bfloat162_rn(make_float2(a, b));   // v_cvt_pk_bf16_f32
    return v.u;
}

__device__ __forceinline__ bf16x8 cvt8(float4 a, float4 b){
    union { unsigned u[4]; bf16x8 v; } r;
    r.u[0] = pk2(a.x, a.y); r.u[1] = pk2(a.z, a.w);
    r.u[2] = pk2(b.x, b.y); r.u[3] = pk2(b.z, b.w);
    return r.v;
}

// ---------------------------------------------------------------------------
// Kernel 0: transpose+convert  x [B][C][N] f32  ->  xT [B][N][C] bf16.
// grid (64 n-tiles, 8 c-tiles, 4 b), block 256.  LDS tile transpose.
// ---------------------------------------------------------------------------
__global__ __launch_bounds__(256) void k0_xt(
    const float* __restrict__ x, unsigned short* __restrict__ xT)
{
    const int n0 = blockIdx.x * 64;
    const int c0 = blockIdx.y * 64;
    const int b  = blockIdx.z;
    const int tid = threadIdx.x;
    __shared__ __align__(16) unsigned short T[64*72];

    {   // load 64(k) x 64(n) fp32 coalesced, convert, store [k][n] bf16
        const int kr = tid >> 2, ns = (tid & 3) * 16;
        const float* xp = x + ((size_t)b*CIN + c0 + kr)*NPIX + n0 + ns;
        float4 a0 = *reinterpret_cast<const float4*>(xp);
        float4 a1 = *reinterpret_cast<const float4*>(xp + 4);
        float4 a2 = *reinterpret_cast<const float4*>(xp + 8);
        float4 a3 = *reinterpret_cast<const float4*>(xp + 12);
        *reinterpret_cast<bf16x8*>(&T[kr*72 + ns])     = cvt8(a0, a1);
        *reinterpret_cast<bf16x8*>(&T[kr*72 + ns + 8]) = cvt8(a2, a3);
    }
    __syncthreads();
    {   // read transposed, write xT rows (k contiguous)
        const int nr = tid >> 2, ks = (tid & 3) * 16;
        unsigned short v[16];
        #pragma unroll
        for (int i=0;i<16;++i) v[i] = T[(ks+i)*72 + nr];
        unsigned short* dst = xT + ((size_t)b*NPIX + n0 + nr)*CIN + c0 + ks;
        *reinterpret_cast<bf16x8*>(dst)     = *reinterpret_cast<bf16x8*>(&v[0]);
        *reinterpret_cast<bf16x8*>(dst + 8) = *reinterpret_cast<bf16x8*>(&v[8]);
    }
}

// ---------------------------------------------------------------------------
// Kernel 1: fused theta/phi/g 1x1 conv via MFMA, with register prefetch of
// the next K-step (T14: global latency hidden under MFMA of current step).
// grid (64 n-tiles, 3 kt, 4 b), block 256 (4 waves).
// ---------------------------------------------------------------------------
__global__ __launch_bounds__(256) void k1_qkv(
    const unsigned short* __restrict__ xT,
    const float* __restrict__ tw, const float* __restrict__ tbv,
    const float* __restrict__ pw, const float* __restrict__ pbv,
    const float* __restrict__ gw, const float* __restrict__ gbv,
    unsigned short* __restrict__ thetaT, unsigned short* __restrict__ phiT,
    unsigned short* __restrict__ g_dn)
{
    const int n0 = blockIdx.x * 64;
    const int kt = blockIdx.y;
    const int b  = blockIdx.z;
    const int tid = threadIdx.x;
    const float* W  = (kt==0) ? tw  : (kt==1) ? pw  : gw;
    const float* Bv = (kt==0) ? tbv : (kt==1) ? pbv : gbv;

    const int wq   = tid >> 6;
    const int lane = tid & 63;
    const int lr   = lane & 15;
    const int lg   = lane >> 4;

    __shared__ __align__(16) short Wt[64*72];   // W tile [m][k] bf16 (pad 8)
    __shared__ __align__(16) short Xt[64*72];   // xT tile [n][k] bf16 (pad 8)

    f32x4 acc[4];
    #pragma unroll
    for (int jt=0;jt<4;++jt) acc[jt] = (f32x4){0.f,0.f,0.f,0.f};

    const int srow = tid >> 2;           // staging row 0..63
    const int skq  = (tid & 3) * 16;     // staging k seg

    float4 w0,w1,w2,w3; bf16x8 x0,x1;
    #define K1LOAD(K) { \
        const float* wp = W + (size_t)srow*CIN + (K) + skq; \
        w0 = *reinterpret_cast<const float4*>(wp); \
        w1 = *reinterpret_cast<const float4*>(wp + 4); \
        w2 = *reinterpret_cast<const float4*>(wp + 8); \
        w3 = *reinterpret_cast<const float4*>(wp + 12); \
        const unsigned short* xp = xT + ((size_t)b*NPIX + n0 + srow)*CIN + (K) + skq; \
        x0 = *reinterpret_cast<const bf16x8*>(xp); \
        x1 = *reinterpret_cast<const bf16x8*>(xp + 8); }

    K1LOAD(0);
    for (int k0 = 0; k0 < CIN; k0 += 64) {
        __syncthreads();
        *reinterpret_cast<bf16x8*>(&Wt[srow*72 + skq])     = cvt8(w0, w1);
        *reinterpret_cast<bf16x8*>(&Wt[srow*72 + skq + 8]) = cvt8(w2, w3);
        *reinterpret_cast<bf16x8*>(&Xt[srow*72 + skq])     = x0;
        *reinterpret_cast<bf16x8*>(&Xt[srow*72 + skq + 8]) = x1;
        __syncthreads();
        if (k0 + 64 < CIN) K1LOAD(k0 + 64);

        __builtin_amdgcn_s_setprio(1);
        #pragma unroll
        for (int dc=0;dc<2;++dc){
            bf16x8 af = *reinterpret_cast<const bf16x8*>(&Wt[(wq*16+lr)*72 + dc*32 + lg*8]);
            #pragma unroll
            for (int jt=0;jt<4;++jt){
                bf16x8 bf = *reinterpret_cast<const bf16x8*>(&Xt[(jt*16+lr)*72 + dc*32 + lg*8]);
                acc[jt] = __builtin_amdgcn_mfma_f32_16x16x32_bf16(af, bf, acc[jt], 0,0,0);
            }
        }
        __builtin_amdgcn_s_setprio(0);
    }

    // acc[jt][r] = out[m = wq*16+lg*4+r][n = n0+jt*16+lr]
    const int mb = wq*16 + lg*4;
    float bv[4];
    #pragma unroll
    for (int r=0;r<4;++r) bv[r] = Bv[mb+r];

    if (kt < 2){
        unsigned short* dst = (kt==0) ? thetaT : phiT;   // [b][n][d], d contig
        #pragma unroll
        for (int jt=0;jt<4;++jt){
            union { unsigned u[2]; u16x4 v; } o;
            o.u[0] = pk2(acc[jt][0]+bv[0], acc[jt][1]+bv[1]);
            o.u[1] = pk2(acc[jt][2]+bv[2], acc[jt][3]+bv[3]);
            *reinterpret_cast<u16x4*>(&dst[((size_t)b*NPIX + n0 + jt*16+lr)*DD + mb]) = o.v;
        }
    } else {
        #pragma unroll
        for (int jt=0;jt<4;++jt)
            #pragma unroll
            for (int r=0;r<4;++r)
                g_dn[((size_t)b*DD + mb+r)*NPIX + n0 + jt*16+lr] = f2bf(acc[jt][r]+bv[r]);
    }
}

// ---------------------------------------------------------------------------
// Kernel 2: MFMA flash attention, KV-chunked, no running max (|S| <~ 10;
// clamp 60 is inf-insurance).  Register prefetch of next KV tile (T14).
// P stored bf16 ROW-MAJOR [q][j] (stride 80: write banks disjoint per lg,
// 2 lanes/bank = free) so the PV A-fragment is a plain contiguous
// ds_read_b128 — no transpose read.
// l via ones-B-fragment MFMA (register constant).
// ---------------------------------------------------------------------------
__global__ __launch_bounds__(256) void k2_attn(
    const unsigned short* __restrict__ thetaT,
    const unsigned short* __restrict__ phiT,
    const unsigned short* __restrict__ g_dn,
    float* __restrict__ pY, float* __restrict__ pL)
{
    const int i0 = blockIdx.x * 64;
    const int ch = blockIdx.y;
    const int b  = blockIdx.z;
    const int tid  = threadIdx.x;
    const int wq   = tid >> 6;        // wave 0..3 -> q strip
    const int lane = tid & 63;
    const int lr   = lane & 15;       // row/col-in-16
    const int lg   = lane >> 4;       // k-group 0..3

    __shared__ __align__(16) short Kt[64*72];      // phiT tile [j][d] bf16 (pad 8)
    __shared__ __align__(16) short Gt[64*72];      // g tile [d][j] bf16 (pad 8)
    __shared__ __align__(16) short Pb[4*16*80];    // per-wave P [q][j] bf16, stride 80
    short* Pw = &Pb[wq*16*80];

    // Q fragments: rows i0+wq*16+lr, k = lg*8..+7 (+32)
    bf16x8 qf[2];
    {
        const unsigned short* qp = thetaT + ((size_t)b*NPIX + i0 + wq*16 + lr)*DD + lg*8;
        qf[0] = *reinterpret_cast<const bf16x8*>(qp);
        qf[1] = *reinterpret_cast<const bf16x8*>(qp + 32);
    }
    const bf16x8 onesf = { (short)0x3F80,(short)0x3F80,(short)0x3F80,(short)0x3F80,
                           (short)0x3F80,(short)0x3F80,(short)0x3F80,(short)0x3F80 };

    f32x4 yacc[4], lacc;
    #pragma unroll
    for (int dt=0;dt<4;++dt) yacc[dt] = (f32x4){0.f,0.f,0.f,0.f};
    lacc = (f32x4){0.f,0.f,0.f,0.f};

    const unsigned short* phb = phiT + (size_t)b*NPIX*DD;
    const unsigned short* gb  = g_dn + (size_t)b*DD*NPIX;

    const int jbeg = ch * (NPIX / NCHUNK);
    const int jend = jbeg + (NPIX / NCHUNK);

    const int srow = tid >> 3;          // 0..31 (two passes: +0, +32)
    const int scb  = (tid & 7) * 8;     // bf16 col seg
    float4 kreg[2], greg[2];
    #define K2LOAD(J) { \
        kreg[0] = *reinterpret_cast<const float4*>(&phb[(size_t)((J)+srow)*DD + scb]); \
        kreg[1] = *reinterpret_cast<const float4*>(&phb[(size_t)((J)+srow+32)*DD + scb]); \
        greg[0] = *reinterpret_cast<const float4*>(&gb[(size_t)srow*NPIX + (J) + scb]); \
        greg[1] = *reinterpret_cast<const float4*>(&gb[(size_t)(srow+32)*NPIX + (J) + scb]); }

    K2LOAD(jbeg);
    for (int j0 = jbeg; j0 < jend; j0 += 64) {
        __syncthreads();                          // prev-tile reads of Kt/Gt done
        *reinterpret_cast<float4*>(&Kt[srow*72 + scb])      = kreg[0];
        *reinterpret_cast<float4*>(&Kt[(srow+32)*72 + scb]) = kreg[1];
        *reinterpret_cast<float4*>(&Gt[srow*72 + scb])      = greg[0];
        *reinterpret_cast<float4*>(&Gt[(srow+32)*72 + scb]) = greg[1];
        __syncthreads();
        if (j0 + 64 < jend) K2LOAD(j0 + 64);      // prefetch: latency hides here

        // ---- S strip: 16q x 64j in 4 accumulators ----
        f32x4 s[4];
        #pragma unroll
        for (int jt=0;jt<4;++jt) s[jt] = (f32x4){0.f,0.f,0.f,0.f};
        __builtin_amdgcn_s_setprio(1);
        #pragma unroll
        for (int dc=0;dc<2;++dc){
            #pragma unroll
            for (int jt=0;jt<4;++jt){
                bf16x8 bf = *reinterpret_cast<const bf16x8*>(&Kt[(jt*16+lr)*72 + dc*32 + lg*8]);
                s[jt] = __builtin_amdgcn_mfma_f32_16x16x32_bf16(qf[dc], bf, s[jt], 0,0,0);
            }
        }
        __builtin_amdgcn_s_setprio(0);

        // ---- p = exp(S) -> bf16 P[q][j] (acc: q=lg*4+r, j=jt*16+lr) ----
        #pragma unroll
        for (int jt=0;jt<4;++jt)
            #pragma unroll
            for (int r=0;r<4;++r){
                float p = __expf(fminf(s[jt][r], 60.f));
                Pw[(lg*4+r)*80 + jt*16 + lr] = (short)f2bf(p);
            }
        // same-wave write->read: compiler inserts lgkmcnt waits

        // ---- PV: yacc[q][d] += P . g ; lacc[q] += P . 1 ----
        __builtin_amdgcn_s_setprio(1);
        #pragma unroll
        for (int jc=0;jc<2;++jc){
            bf16x8 af = *reinterpret_cast<const bf16x8*>(&Pw[lr*80 + jc*32 + lg*8]);
            #pragma unroll
            for (int dt=0;dt<4;++dt){
                bf16x8 gf = *reinterpret_cast<const bf16x8*>(&Gt[(dt*16+lr)*72 + jc*32 + lg*8]);
                yacc[dt] = __builtin_amdgcn_mfma_f32_16x16x32_bf16(af, gf, yacc[dt], 0,0,0);
            }
            lacc = __builtin_amdgcn_mfma_f32_16x16x32_bf16(af, onesf, lacc, 0,0,0);
        }
        __builtin_amdgcn_s_setprio(0);
    }

    // ---- epilogue: store UNNORMALIZED partial + l ----
    float* py = pY + (((size_t)b*NCHUNK + ch)*NPIX + i0 + wq*16)*DD;
    #pragma unroll
    for (int r=0;r<4;++r){
        #pragma unroll
        for (int dt=0;dt<4;++dt)
            py[(size_t)(lg*4+r)*DD + dt*16 + lr] = yacc[dt][r];
    }
    if (lr == 0){                                  // lacc cols all equal l[q]
        const size_t base = ((size_t)b*NCHUNK + ch)*NPIX + i0 + wq*16;
        #pragma unroll
        for (int r=0;r<4;++r)
            pL[base + lg*4+r] = lacc[r];
    }
}

// ---------------------------------------------------------------------------
// Kernel 2c: combine partials (plain sums), emit bf16 yT [B][N][D].
// ---------------------------------------------------------------------------
__global__ __launch_bounds__(256) void k2c_combine(
    const float* __restrict__ pY, const float* __restrict__ pL,
    unsigned short* __restrict__ yTb)
{
    const int gid = blockIdx.x*256 + threadIdx.x;   // B*N*DD total
    const int d  = gid & (DD-1);
    const int qn = gid >> 6;          // b*NPIX + i
    const int b  = qn >> 12;
    const int i  = qn & (NPIX-1);

    float lsum = 0.f, y = 0.f;
    #pragma unroll
    for (int c=0;c<NCHUNK;++c){
        lsum += pL[((size_t)b*NCHUNK + c)*NPIX + i];
        y    += pY[(((size_t)b*NCHUNK + c)*NPIX + i)*DD + d];
    }
    yTb[(size_t)qn*DD + d] = f2bf(y / lsum);
}

// ---------------------------------------------------------------------------
// Kernel 3: out conv via MFMA + FUSED deterministic BN partial stats.
// grid (64 n-tiles, 8 c-tiles, 4 b), block 256.
// partial sums: psum/qsum [512 c][256 slot], slot = b*64 + n-tile.
// ---------------------------------------------------------------------------
__global__ __launch_bounds__(256) void k3_out(
    const unsigned short* __restrict__ yTb, const float* __restrict__ ow,
    const float* __restrict__ ob, float* __restrict__ y2,
    float* __restrict__ psum, float* __restrict__ qsum)
{
    const int n0 = blockIdx.x * 64;
    const int c0 = blockIdx.y * 64;
    const int b  = blockIdx.z;
    const int tid = threadIdx.x;
    const int wq   = tid >> 6;
    const int lane = tid & 63;
    const int lr   = lane & 15;
    const int lg   = lane >> 4;

    __shared__ __align__(16) short Ot[64*72];
    __shared__ __align__(16) short Yt[64*72];

    {   // stage ow [64 c][64 d] fp32 -> bf16 ; yTb [64 n][64 d] bf16
        const int srow = tid >> 2, skq = (tid & 3) * 16;
        const float* wp = ow + (size_t)(c0+srow)*DD + skq;
        float4 w0 = *reinterpret_cast<const float4*>(wp);
        float4 w1 = *reinterpret_cast<const float4*>(wp + 4);
        float4 w2 = *reinterpret_cast<const float4*>(wp + 8);
        float4 w3 = *reinterpret_cast<const float4*>(wp + 12);
        *reinterpret_cast<bf16x8*>(&Ot[srow*72 + skq])     = cvt8(w0, w1);
        *reinterpret_cast<bf16x8*>(&Ot[srow*72 + skq + 8]) = cvt8(w2, w3);
        const unsigned short* yp = yTb + ((size_t)b*NPIX + n0 + srow)*DD + skq;
        *reinterpret_cast<bf16x8*>(&Yt[srow*72 + skq]) =
            *reinterpret_cast<const bf16x8*>(yp);
        *reinterpret_cast<bf16x8*>(&Yt[srow*72 + skq + 8]) =
            *reinterpret_cast<const bf16x8*>(yp + 8);
    }
    __syncthreads();

    f32x4 acc[4];
    #pragma unroll
    for (int jt=0;jt<4;++jt) acc[jt] = (f32x4){0.f,0.f,0.f,0.f};
    #pragma unroll
    for (int dc=0;dc<2;++dc){
        bf16x8 af = *reinterpret_cast<const bf16x8*>(&Ot[(wq*16+lr)*72 + dc*32 + lg*8]);
        #pragma unroll
        for (int jt=0;jt<4;++jt){
            bf16x8 bf = *reinterpret_cast<const bf16x8*>(&Yt[(jt*16+lr)*72 + dc*32 + lg*8]);
            acc[jt] = __builtin_amdgcn_mfma_f32_16x16x32_bf16(af, bf, acc[jt], 0,0,0);
        }
    }

    const int cb = c0 + wq*16 + lg*4;
    float bv[4];
    #pragma unroll
    for (int r=0;r<4;++r) bv[r] = ob[cb+r];

    float sr[4] = {0,0,0,0}, qr[4] = {0,0,0,0};
    #pragma unroll
    for (int jt=0;jt<4;++jt)
        #pragma unroll
        for (int r=0;r<4;++r){
            float v = acc[jt][r] + bv[r];
            y2[((size_t)b*CIN + cb+r)*NPIX + n0 + jt*16+lr] = v;
            sr[r] += v; qr[r] += v*v;
        }
    // reduce over lr (lane bits 0..3) -> per-channel partials for 64 n
    #pragma unroll
    for (int off=1; off<16; off<<=1)
        #pragma unroll
        for (int r=0;r<4;++r){
            sr[r] += __shfl_xor(sr[r], off);
            qr[r] += __shfl_xor(qr[r], off);
        }
    if (lr == 0){
        const int slot = b*64 + blockIdx.x;
        #pragma unroll
        for (int r=0;r<4;++r){
            psum[(size_t)(cb+r)*256 + slot] = sr[r];
            qsum[(size_t)(cb+r)*256 + slot] = qr[r];
        }
    }
}

// ---------------------------------------------------------------------------
// Kernel 3b: reduce [512][256] partials -> mean/inv (deterministic tree).
// ---------------------------------------------------------------------------
__global__ __launch_bounds__(256) void k3b_stats(
    const float* __restrict__ psum, const float* __restrict__ qsum,
    float* __restrict__ meanA, float* __restrict__ invA)
{
    const int c = blockIdx.x;
    const int tid = threadIdx.x;
    float s = psum[(size_t)c*256 + tid];
    float q = qsum[(size_t)c*256 + tid];
    __shared__ float rs[256], rq[256];
    rs[tid]=s; rq[tid]=q; __syncthreads();
    for (int off=128; off; off>>=1){
        if (tid<off){ rs[tid]+=rs[tid+off]; rq[tid]+=rq[tid+off]; }
        __syncthreads();
    }
    if (tid==0){
        const float n = (float)(BB*NPIX);
        float mm = rs[0] / n;
        float v = rq[0] / n - mm*mm;
        meanA[c]=mm; invA[c]=rsqrtf(v + 1e-5f);
    }
}

// ---------------------------------------------------------------------------
// Kernel 4: in-place BN apply + residual.
// ---------------------------------------------------------------------------
__global__ __launch_bounds__(256) void k4_final(
    const float* __restrict__ x,
    const float* __restrict__ meanA, const float* __restrict__ invA,
    const float* __restrict__ gamma, const float* __restrict__ beta,
    const float* __restrict__ scale, float* out /*aliases y2*/)
{
    const float sc = scale[0];
    const int total4 = BB*CIN*NPIX/4;
    for (int i4 = blockIdx.x*blockDim.x + threadIdx.x; i4 < total4;
         i4 += gridDim.x*blockDim.x){
        int c = (i4 >> 10) & (CIN-1);
        float4 xv = reinterpret_cast<const float4*>(x)[i4];
        float4 yv = reinterpret_cast<float4*>(out)[i4];
        float mm = meanA[c], iv = invA[c], g = gamma[c], bt = beta[c];
        float4 o;
        o.x = xv.x + sc*(g*(yv.x-mm)*iv + bt);
        o.y = xv.y + sc*(g*(yv.y-mm)*iv + bt);
        o.z = xv.z + sc*(g*(yv.z-mm)*iv + bt);
        o.w = xv.w + sc*(g*(yv.w-mm)*iv + bt);
        reinterpret_cast<float4*>(out)[i4] = o;
    }
}

// ---------------------------------------------------------------------------
extern "C" void kernel_launch(void* const* d_in, const int* in_sizes, int n_in,
                              void* d_out, int out_size, void* d_ws, size_t ws_size,
                              hipStream_t stream)
{
    const float* x     = (const float*)d_in[0];
    const float* tw    = (const float*)d_in[1];
    const float* tbv   = (const float*)d_in[2];
    const float* pw    = (const float*)d_in[3];
    const float* pbv   = (const float*)d_in[4];
    const float* gw    = (const float*)d_in[5];
    const float* gbv   = (const float*)d_in[6];
    const float* ow    = (const float*)d_in[7];
    const float* ob    = (const float*)d_in[8];
    const float* gamma = (const float*)d_in[9];
    const float* beta  = (const float*)d_in[10];
    const float* scale = (const float*)d_in[11];
    float* out = (float*)d_out;

    char* wsb = (char*)d_ws;
    unsigned short* thetaT = (unsigned short*)(wsb);             // 2 MB
    unsigned short* phiT   = (unsigned short*)(wsb + 2097152);   // 2 MB
    unsigned short* g_dn   = (unsigned short*)(wsb + 4194304);   // 2 MB
    unsigned short* yTb    = (unsigned short*)(wsb + 6291456);   // 2 MB
    float*          pL     = (float*)(wsb + 8388608);            // 512 KB
    float*          psum   = (float*)(wsb + 8912896);            // 512 KB
    float*          qsum   = (float*)(wsb + 9437184);            // 512 KB
    float*          meanA  = (float*)(wsb + 9961472);
    float*          invA   = (float*)(wsb + 9963520);

    // d_out (33.5 MB) is time-shared scratch:
    //   phase A: xT [B][N][C] bf16 (16.8 MB)  -- k0 writes, k1 reads
    //   phase B: pY [B][NCHUNK][N][D] f32 (33.5 MB) -- k2 writes, k2c reads
    //   phase C: y2 [B][C][N] f32 -- k3 writes, k4 reads/writes final
    unsigned short* xT = (unsigned short*)d_out;
    float* pY = out;
    float* y2 = out;

    k0_xt  <<<dim3(64,8,4), 256, 0, stream>>>(x, xT);
    k1_qkv <<<dim3(64,3,4), 256, 0, stream>>>(xT, tw, tbv, pw, pbv, gw, gbv,
                                              thetaT, phiT, g_dn);
    k2_attn<<<dim3(64,NCHUNK,4), 256, 0, stream>>>(thetaT, phiT, g_dn, pY, pL);
    k2c_combine<<<4096, 256, 0, stream>>>(pY, pL, yTb);
    k3_out <<<dim3(64,8,4), 256, 0, stream>>>(yTb, ow, ob, y2, psum, qsum);
    k3b_stats<<<512, 256, 0, stream>>>(psum, qsum, meanA, invA);
    k4_final<<<2048, 256, 0, stream>>>(x, meanA, invA, gamma, beta, scale, out);
}

// Round 8
// 136.356 us; speedup vs baseline: 1.0358x; 1.0358x over previous
//
#include <hip/hip_runtime.h>
#include <hip/hip_bf16.h>
#include <math.h>

#define NPIX 4096   // H*W
#define CIN  512
#define DD   64
#define BB   4
#define NCHUNK 8    // KV chunks for flash-decode split (chunk = 512)

using f32x4  = __attribute__((ext_vector_type(4))) float;
using bf16x8 = __attribute__((ext_vector_type(8))) short;
using u16x4  = __attribute__((ext_vector_type(4))) unsigned short;

__device__ __forceinline__ unsigned short f2bf(float f){
    union { __hip_bfloat16 h; unsigned short u; } v;
    v.h = __float2bfloat16(f);            // RNE
    return v.u;
}

__device__ __forceinline__ unsigned pk2(float a, float b){
    union { __hip_bfloat162 h; unsigned u; } v;
    v.h = __float22bfloat162_rn(make_float2(a, b));   // v_cvt_pk_bf16_f32
    return v.u;
}

__device__ __forceinline__ bf16x8 cvt8(float4 a, float4 b){
    union { unsigned u[4]; bf16x8 v; } r;
    r.u[0] = pk2(a.x, a.y); r.u[1] = pk2(a.z, a.w);
    r.u[2] = pk2(b.x, b.y); r.u[3] = pk2(b.z, b.w);
    return r.v;
}

// ---------------------------------------------------------------------------
// Kernel 0: transpose+convert  x [B][C][N] f32  ->  xT [B][N][C] bf16.
// grid (64 n-tiles, 8 c-tiles, 4 b), block 256.  LDS tile transpose.
// ---------------------------------------------------------------------------
__global__ __launch_bounds__(256) void k0_xt(
    const float* __restrict__ x, unsigned short* __restrict__ xT)
{
    const int n0 = blockIdx.x * 64;
    const int c0 = blockIdx.y * 64;
    const int b  = blockIdx.z;
    const int tid = threadIdx.x;
    __shared__ __align__(16) unsigned short T[64*72];

    {   // load 64(k) x 64(n) fp32 coalesced, convert, store [k][n] bf16
        const int kr = tid >> 2, ns = (tid & 3) * 16;
        const float* xp = x + ((size_t)b*CIN + c0 + kr)*NPIX + n0 + ns;
        float4 a0 = *reinterpret_cast<const float4*>(xp);
        float4 a1 = *reinterpret_cast<const float4*>(xp + 4);
        float4 a2 = *reinterpret_cast<const float4*>(xp + 8);
        float4 a3 = *reinterpret_cast<const float4*>(xp + 12);
        *reinterpret_cast<bf16x8*>(&T[kr*72 + ns])     = cvt8(a0, a1);
        *reinterpret_cast<bf16x8*>(&T[kr*72 + ns + 8]) = cvt8(a2, a3);
    }
    __syncthreads();
    {   // read transposed, write xT rows (k contiguous)
        const int nr = tid >> 2, ks = (tid & 3) * 16;
        unsigned short v[16];
        #pragma unroll
        for (int i=0;i<16;++i) v[i] = T[(ks+i)*72 + nr];
        unsigned short* dst = xT + ((size_t)b*NPIX + n0 + nr)*CIN + c0 + ks;
        *reinterpret_cast<bf16x8*>(dst)     = *reinterpret_cast<bf16x8*>(&v[0]);
        *reinterpret_cast<bf16x8*>(dst + 8) = *reinterpret_cast<bf16x8*>(&v[8]);
    }
}

// ---------------------------------------------------------------------------
// Kernel 1: fused theta/phi/g 1x1 conv via MFMA.  Prefetch of the next
// K-step issued at TOP of iteration, written to LDS at BOTTOM of the SAME
// iteration (no loop-carried registers across barriers -> no spill).
// grid (64 n-tiles, 3 kt, 4 b), block 256 (4 waves).
// ---------------------------------------------------------------------------
__global__ __launch_bounds__(256, 4) void k1_qkv(
    const unsigned short* __restrict__ xT,
    const float* __restrict__ tw, const float* __restrict__ tbv,
    const float* __restrict__ pw, const float* __restrict__ pbv,
    const float* __restrict__ gw, const float* __restrict__ gbv,
    unsigned short* __restrict__ thetaT, unsigned short* __restrict__ phiT,
    unsigned short* __restrict__ g_dn)
{
    const int n0 = blockIdx.x * 64;
    const int kt = blockIdx.y;
    const int b  = blockIdx.z;
    const int tid = threadIdx.x;
    const float* W  = (kt==0) ? tw  : (kt==1) ? pw  : gw;
    const float* Bv = (kt==0) ? tbv : (kt==1) ? pbv : gbv;

    const int wq   = tid >> 6;
    const int lane = tid & 63;
    const int lr   = lane & 15;
    const int lg   = lane >> 4;

    __shared__ __align__(16) short Wt[64*72];   // W tile [m][k] bf16 (pad 8)
    __shared__ __align__(16) short Xt[64*72];   // xT tile [n][k] bf16 (pad 8)

    f32x4 acc[4];
    #pragma unroll
    for (int jt=0;jt<4;++jt) acc[jt] = (f32x4){0.f,0.f,0.f,0.f};

    const int srow = tid >> 2;           // staging row 0..63
    const int skq  = (tid & 3) * 16;     // staging k seg

    float4 w0,w1,w2,w3; bf16x8 x0,x1;
    #define K1LOAD(K) { \
        const float* wp = W + (size_t)srow*CIN + (K) + skq; \
        w0 = *reinterpret_cast<const float4*>(wp); \
        w1 = *reinterpret_cast<const float4*>(wp + 4); \
        w2 = *reinterpret_cast<const float4*>(wp + 8); \
        w3 = *reinterpret_cast<const float4*>(wp + 12); \
        const unsigned short* xp = xT + ((size_t)b*NPIX + n0 + srow)*CIN + (K) + skq; \
        x0 = *reinterpret_cast<const bf16x8*>(xp); \
        x1 = *reinterpret_cast<const bf16x8*>(xp + 8); }
    #define K1STORE() { \
        *reinterpret_cast<bf16x8*>(&Wt[srow*72 + skq])     = cvt8(w0, w1); \
        *reinterpret_cast<bf16x8*>(&Wt[srow*72 + skq + 8]) = cvt8(w2, w3); \
        *reinterpret_cast<bf16x8*>(&Xt[srow*72 + skq])     = x0; \
        *reinterpret_cast<bf16x8*>(&Xt[srow*72 + skq + 8]) = x1; }

    K1LOAD(0);
    K1STORE();
    __syncthreads();

    for (int k0 = 0; k0 < CIN; k0 += 64) {
        const bool more = (k0 + 64 < CIN);
        if (more) K1LOAD(k0 + 64);       // issue early; consumed end of iter

        __builtin_amdgcn_s_setprio(1);
        #pragma unroll
        for (int dc=0;dc<2;++dc){
            bf16x8 af = *reinterpret_cast<const bf16x8*>(&Wt[(wq*16+lr)*72 + dc*32 + lg*8]);
            #pragma unroll
            for (int jt=0;jt<4;++jt){
                bf16x8 bf = *reinterpret_cast<const bf16x8*>(&Xt[(jt*16+lr)*72 + dc*32 + lg*8]);
                acc[jt] = __builtin_amdgcn_mfma_f32_16x16x32_bf16(af, bf, acc[jt], 0,0,0);
            }
        }
        __builtin_amdgcn_s_setprio(0);

        if (more){
            __syncthreads();             // all waves done reading Wt/Xt
            K1STORE();                   // vmcnt wait lands here, post-compute
            __syncthreads();
        }
    }

    // acc[jt][r] = out[m = wq*16+lg*4+r][n = n0+jt*16+lr]
    const int mb = wq*16 + lg*4;
    float bv[4];
    #pragma unroll
    for (int r=0;r<4;++r) bv[r] = Bv[mb+r];

    if (kt < 2){
        unsigned short* dst = (kt==0) ? thetaT : phiT;   // [b][n][d], d contig
        #pragma unroll
        for (int jt=0;jt<4;++jt){
            union { unsigned u[2]; u16x4 v; } o;
            o.u[0] = pk2(acc[jt][0]+bv[0], acc[jt][1]+bv[1]);
            o.u[1] = pk2(acc[jt][2]+bv[2], acc[jt][3]+bv[3]);
            *reinterpret_cast<u16x4*>(&dst[((size_t)b*NPIX + n0 + jt*16+lr)*DD + mb]) = o.v;
        }
    } else {
        #pragma unroll
        for (int jt=0;jt<4;++jt)
            #pragma unroll
            for (int r=0;r<4;++r)
                g_dn[((size_t)b*DD + mb+r)*NPIX + n0 + jt*16+lr] = f2bf(acc[jt][r]+bv[r]);
    }
}

// ---------------------------------------------------------------------------
// Kernel 2: MFMA flash attention, KV-chunked, no running max (|S| <~ 10;
// clamp 60 is inf-insurance).  Next-tile loads issued at TOP of iteration,
// LDS-written at BOTTOM of the same iteration (no cross-barrier reg carry).
// P stored bf16 row-major [q][j] stride 72 (read b128 2-way = free).
// l via ones-B-fragment MFMA.
// ---------------------------------------------------------------------------
__global__ __launch_bounds__(256, 4) void k2_attn(
    const unsigned short* __restrict__ thetaT,
    const unsigned short* __restrict__ phiT,
    const unsigned short* __restrict__ g_dn,
    float* __restrict__ pY, float* __restrict__ pL)
{
    const int i0 = blockIdx.x * 64;
    const int ch = blockIdx.y;
    const int b  = blockIdx.z;
    const int tid  = threadIdx.x;
    const int wq   = tid >> 6;        // wave 0..3 -> q strip
    const int lane = tid & 63;
    const int lr   = lane & 15;       // row/col-in-16
    const int lg   = lane >> 4;       // k-group 0..3

    __shared__ __align__(16) short Kt[64*72];      // phiT tile [j][d] bf16 (pad 8)
    __shared__ __align__(16) short Gt[64*72];      // g tile [d][j] bf16 (pad 8)
    __shared__ __align__(16) short Pb[4*16*72];    // per-wave P [q][j] bf16, stride 72
    short* Pw = &Pb[wq*16*72];

    // Q fragments: rows i0+wq*16+lr, k = lg*8..+7 (+32)
    bf16x8 qf[2];
    {
        const unsigned short* qp = thetaT + ((size_t)b*NPIX + i0 + wq*16 + lr)*DD + lg*8;
        qf[0] = *reinterpret_cast<const bf16x8*>(qp);
        qf[1] = *reinterpret_cast<const bf16x8*>(qp + 32);
    }
    const bf16x8 onesf = { (short)0x3F80,(short)0x3F80,(short)0x3F80,(short)0x3F80,
                           (short)0x3F80,(short)0x3F80,(short)0x3F80,(short)0x3F80 };

    f32x4 yacc[4], lacc;
    #pragma unroll
    for (int dt=0;dt<4;++dt) yacc[dt] = (f32x4){0.f,0.f,0.f,0.f};
    lacc = (f32x4){0.f,0.f,0.f,0.f};

    const unsigned short* phb = phiT + (size_t)b*NPIX*DD;
    const unsigned short* gb  = g_dn + (size_t)b*DD*NPIX;

    const int jbeg = ch * (NPIX / NCHUNK);
    const int jend = jbeg + (NPIX / NCHUNK);

    const int srow = tid >> 3;          // 0..31 (two passes: +0, +32)
    const int scb  = (tid & 7) * 8;     // bf16 col seg
    float4 kreg[2], greg[2];
    #define K2LOAD(J) { \
        kreg[0] = *reinterpret_cast<const float4*>(&phb[(size_t)((J)+srow)*DD + scb]); \
        kreg[1] = *reinterpret_cast<const float4*>(&phb[(size_t)((J)+srow+32)*DD + scb]); \
        greg[0] = *reinterpret_cast<const float4*>(&gb[(size_t)srow*NPIX + (J) + scb]); \
        greg[1] = *reinterpret_cast<const float4*>(&gb[(size_t)(srow+32)*NPIX + (J) + scb]); }
    #define K2STORE() { \
        *reinterpret_cast<float4*>(&Kt[srow*72 + scb])      = kreg[0]; \
        *reinterpret_cast<float4*>(&Kt[(srow+32)*72 + scb]) = kreg[1]; \
        *reinterpret_cast<float4*>(&Gt[srow*72 + scb])      = greg[0]; \
        *reinterpret_cast<float4*>(&Gt[(srow+32)*72 + scb]) = greg[1]; }

    K2LOAD(jbeg);
    K2STORE();
    __syncthreads();

    for (int j0 = jbeg; j0 < jend; j0 += 64) {
        const bool more = (j0 + 64 < jend);
        if (more) K2LOAD(j0 + 64);        // issue early; LDS-write end of iter

        // ---- S strip: 16q x 64j in 4 accumulators ----
        f32x4 s[4];
        #pragma unroll
        for (int jt=0;jt<4;++jt) s[jt] = (f32x4){0.f,0.f,0.f,0.f};
        __builtin_amdgcn_s_setprio(1);
        #pragma unroll
        for (int dc=0;dc<2;++dc){
            #pragma unroll
            for (int jt=0;jt<4;++jt){
                bf16x8 bf = *reinterpret_cast<const bf16x8*>(&Kt[(jt*16+lr)*72 + dc*32 + lg*8]);
                s[jt] = __builtin_amdgcn_mfma_f32_16x16x32_bf16(qf[dc], bf, s[jt], 0,0,0);
            }
        }
        __builtin_amdgcn_s_setprio(0);

        // ---- p = exp(S) -> bf16 P[q][j] (acc: q=lg*4+r, j=jt*16+lr) ----
        #pragma unroll
        for (int jt=0;jt<4;++jt)
            #pragma unroll
            for (int r=0;r<4;++r){
                float p = __expf(fminf(s[jt][r], 60.f));
                Pw[(lg*4+r)*72 + jt*16 + lr] = (short)f2bf(p);
            }
        // same-wave write->read: compiler inserts lgkmcnt waits

        // ---- PV: yacc[q][d] += P . g ; lacc[q] += P . 1 ----
        __builtin_amdgcn_s_setprio(1);
        #pragma unroll
        for (int jc=0;jc<2;++jc){
            bf16x8 af = *reinterpret_cast<const bf16x8*>(&Pw[lr*72 + jc*32 + lg*8]);
            #pragma unroll
            for (int dt=0;dt<4;++dt){
                bf16x8 gf = *reinterpret_cast<const bf16x8*>(&Gt[(dt*16+lr)*72 + jc*32 + lg*8]);
                yacc[dt] = __builtin_amdgcn_mfma_f32_16x16x32_bf16(af, gf, yacc[dt], 0,0,0);
            }
            lacc = __builtin_amdgcn_mfma_f32_16x16x32_bf16(af, onesf, lacc, 0,0,0);
        }
        __builtin_amdgcn_s_setprio(0);

        if (more){
            __syncthreads();              // all waves done reading Kt/Gt
            K2STORE();                    // vmcnt wait here, after compute
            __syncthreads();
        }
    }

    // ---- epilogue: store UNNORMALIZED partial + l ----
    float* py = pY + (((size_t)b*NCHUNK + ch)*NPIX + i0 + wq*16)*DD;
    #pragma unroll
    for (int r=0;r<4;++r){
        #pragma unroll
        for (int dt=0;dt<4;++dt)
            py[(size_t)(lg*4+r)*DD + dt*16 + lr] = yacc[dt][r];
    }
    if (lr == 0){                                  // lacc cols all equal l[q]
        const size_t base = ((size_t)b*NCHUNK + ch)*NPIX + i0 + wq*16;
        #pragma unroll
        for (int r=0;r<4;++r)
            pL[base + lg*4+r] = lacc[r];
    }
}

// ---------------------------------------------------------------------------
// Kernel 2c: combine partials (plain sums), emit bf16 yT [B][N][D].
// ---------------------------------------------------------------------------
__global__ __launch_bounds__(256) void k2c_combine(
    const float* __restrict__ pY, const float* __restrict__ pL,
    unsigned short* __restrict__ yTb)
{
    const int gid = blockIdx.x*256 + threadIdx.x;   // B*N*DD total
    const int d  = gid & (DD-1);
    const int qn = gid >> 6;          // b*NPIX + i
    const int b  = qn >> 12;
    const int i  = qn & (NPIX-1);

    float lsum = 0.f, y = 0.f;
    #pragma unroll
    for (int c=0;c<NCHUNK;++c){
        lsum += pL[((size_t)b*NCHUNK + c)*NPIX + i];
        y    += pY[(((size_t)b*NCHUNK + c)*NPIX + i)*DD + d];
    }
    yTb[(size_t)qn*DD + d] = f2bf(y / lsum);
}

// ---------------------------------------------------------------------------
// Kernel 3: out conv via MFMA + FUSED deterministic BN partial stats.
// grid (64 n-tiles, 8 c-tiles, 4 b), block 256.
// partial sums: psum/qsum [512 c][256 slot], slot = b*64 + n-tile.
// ---------------------------------------------------------------------------
__global__ __launch_bounds__(256) void k3_out(
    const unsigned short* __restrict__ yTb, const float* __restrict__ ow,
    const float* __restrict__ ob, float* __restrict__ y2,
    float* __restrict__ psum, float* __restrict__ qsum)
{
    const int n0 = blockIdx.x * 64;
    const int c0 = blockIdx.y * 64;
    const int b  = blockIdx.z;
    const int tid = threadIdx.x;
    const int wq   = tid >> 6;
    const int lane = tid & 63;
    const int lr   = lane & 15;
    const int lg   = lane >> 4;

    __shared__ __align__(16) short Ot[64*72];
    __shared__ __align__(16) short Yt[64*72];

    {   // stage ow [64 c][64 d] fp32 -> bf16 ; yTb [64 n][64 d] bf16
        const int srow = tid >> 2, skq = (tid & 3) * 16;
        const float* wp = ow + (size_t)(c0+srow)*DD + skq;
        float4 w0 = *reinterpret_cast<const float4*>(wp);
        float4 w1 = *reinterpret_cast<const float4*>(wp + 4);
        float4 w2 = *reinterpret_cast<const float4*>(wp + 8);
        float4 w3 = *reinterpret_cast<const float4*>(wp + 12);
        *reinterpret_cast<bf16x8*>(&Ot[srow*72 + skq])     = cvt8(w0, w1);
        *reinterpret_cast<bf16x8*>(&Ot[srow*72 + skq + 8]) = cvt8(w2, w3);
        const unsigned short* yp = yTb + ((size_t)b*NPIX + n0 + srow)*DD + skq;
        *reinterpret_cast<bf16x8*>(&Yt[srow*72 + skq]) =
            *reinterpret_cast<const bf16x8*>(yp);
        *reinterpret_cast<bf16x8*>(&Yt[srow*72 + skq + 8]) =
            *reinterpret_cast<const bf16x8*>(yp + 8);
    }
    __syncthreads();

    f32x4 acc[4];
    #pragma unroll
    for (int jt=0;jt<4;++jt) acc[jt] = (f32x4){0.f,0.f,0.f,0.f};
    #pragma unroll
    for (int dc=0;dc<2;++dc){
        bf16x8 af = *reinterpret_cast<const bf16x8*>(&Ot[(wq*16+lr)*72 + dc*32 + lg*8]);
        #pragma unroll
        for (int jt=0;jt<4;++jt){
            bf16x8 bf = *reinterpret_cast<const bf16x8*>(&Yt[(jt*16+lr)*72 + dc*32 + lg*8]);
            acc[jt] = __builtin_amdgcn_mfma_f32_16x16x32_bf16(af, bf, acc[jt], 0,0,0);
        }
    }

    const int cb = c0 + wq*16 + lg*4;
    float bv[4];
    #pragma unroll
    for (int r=0;r<4;++r) bv[r] = ob[cb+r];

    float sr[4] = {0,0,0,0}, qr[4] = {0,0,0,0};
    #pragma unroll
    for (int jt=0;jt<4;++jt)
        #pragma unroll
        for (int r=0;r<4;++r){
            float v = acc[jt][r] + bv[r];
            y2[((size_t)b*CIN + cb+r)*NPIX + n0 + jt*16+lr] = v;
            sr[r] += v; qr[r] += v*v;
        }
    // reduce over lr (lane bits 0..3) -> per-channel partials for 64 n
    #pragma unroll
    for (int off=1; off<16; off<<=1)
        #pragma unroll
        for (int r=0;r<4;++r){
            sr[r] += __shfl_xor(sr[r], off);
            qr[r] += __shfl_xor(qr[r], off);
        }
    if (lr == 0){
        const int slot = b*64 + blockIdx.x;
        #pragma unroll
        for (int r=0;r<4;++r){
            psum[(size_t)(cb+r)*256 + slot] = sr[r];
            qsum[(size_t)(cb+r)*256 + slot] = qr[r];
        }
    }
}

// ---------------------------------------------------------------------------
// Kernel 3b: reduce [512][256] partials -> mean/inv (deterministic tree).
// ---------------------------------------------------------------------------
__global__ __launch_bounds__(256) void k3b_stats(
    const float* __restrict__ psum, const float* __restrict__ qsum,
    float* __restrict__ meanA, float* __restrict__ invA)
{
    const int c = blockIdx.x;
    const int tid = threadIdx.x;
    float s = psum[(size_t)c*256 + tid];
    float q = qsum[(size_t)c*256 + tid];
    __shared__ float rs[256], rq[256];
    rs[tid]=s; rq[tid]=q; __syncthreads();
    for (int off=128; off; off>>=1){
        if (tid<off){ rs[tid]+=rs[tid+off]; rq[tid]+=rq[tid+off]; }
        __syncthreads();
    }
    if (tid==0){
        const float n = (float)(BB*NPIX);
        float mm = rs[0] / n;
        float v = rq[0] / n - mm*mm;
        meanA[c]=mm; invA[c]=rsqrtf(v + 1e-5f);
    }
}

// ---------------------------------------------------------------------------
// Kernel 4: in-place BN apply + residual.
// ---------------------------------------------------------------------------
__global__ __launch_bounds__(256) void k4_final(
    const float* __restrict__ x,
    const float* __restrict__ meanA, const float* __restrict__ invA,
    const float* __restrict__ gamma, const float* __restrict__ beta,
    const float* __restrict__ scale, float* out /*aliases y2*/)
{
    const float sc = scale[0];
    const int total4 = BB*CIN*NPIX/4;
    for (int i4 = blockIdx.x*blockDim.x + threadIdx.x; i4 < total4;
         i4 += gridDim.x*blockDim.x){
        int c = (i4 >> 10) & (CIN-1);
        float4 xv = reinterpret_cast<const float4*>(x)[i4];
        float4 yv = reinterpret_cast<float4*>(out)[i4];
        float mm = meanA[c], iv = invA[c], g = gamma[c], bt = beta[c];
        float4 o;
        o.x = xv.x + sc*(g*(yv.x-mm)*iv + bt);
        o.y = xv.y + sc*(g*(yv.y-mm)*iv + bt);
        o.z = xv.z + sc*(g*(yv.z-mm)*iv + bt);
        o.w = xv.w + sc*(g*(yv.w-mm)*iv + bt);
        reinterpret_cast<float4*>(out)[i4] = o;
    }
}

// ---------------------------------------------------------------------------
extern "C" void kernel_launch(void* const* d_in, const int* in_sizes, int n_in,
                              void* d_out, int out_size, void* d_ws, size_t ws_size,
                              hipStream_t stream)
{
    const float* x     = (const float*)d_in[0];
    const float* tw    = (const float*)d_in[1];
    const float* tbv   = (const float*)d_in[2];
    const float* pw    = (const float*)d_in[3];
    const float* pbv   = (const float*)d_in[4];
    const float* gw    = (const float*)d_in[5];
    const float* gbv   = (const float*)d_in[6];
    const float* ow    = (const float*)d_in[7];
    const float* ob    = (const float*)d_in[8];
    const float* gamma = (const float*)d_in[9];
    const float* beta  = (const float*)d_in[10];
    const float* scale = (const float*)d_in[11];
    float* out = (float*)d_out;

    char* wsb = (char*)d_ws;
    unsigned short* thetaT = (unsigned short*)(wsb);             // 2 MB
    unsigned short* phiT   = (unsigned short*)(wsb + 2097152);   // 2 MB
    unsigned short* g_dn   = (unsigned short*)(wsb + 4194304);   // 2 MB
    unsigned short* yTb    = (unsigned short*)(wsb + 6291456);   // 2 MB
    float*          pL     = (float*)(wsb + 8388608);            // 512 KB
    float*          psum   = (float*)(wsb + 8912896);            // 512 KB
    float*          qsum   = (float*)(wsb + 9437184);            // 512 KB
    float*          meanA  = (float*)(wsb + 9961472);
    float*          invA   = (float*)(wsb + 9963520);

    // d_out (33.5 MB) is time-shared scratch:
    //   phase A: xT [B][N][C] bf16 (16.8 MB)  -- k0 writes, k1 reads
    //   phase B: pY [B][NCHUNK][N][D] f32 (33.5 MB) -- k2 writes, k2c reads
    //   phase C: y2 [B][C][N] f32 -- k3 writes, k4 reads/writes final
    unsigned short* xT = (unsigned short*)d_out;
    float* pY = out;
    float* y2 = out;

    k0_xt  <<<dim3(64,8,4), 256, 0, stream>>>(x, xT);
    k1_qkv <<<dim3(64,3,4), 256, 0, stream>>>(xT, tw, tbv, pw, pbv, gw, gbv,
                                              thetaT, phiT, g_dn);
    k2_attn<<<dim3(64,NCHUNK,4), 256, 0, stream>>>(thetaT, phiT, g_dn, pY, pL);
    k2c_combine<<<4096, 256, 0, stream>>>(pY, pL, yTb);
    k3_out <<<dim3(64,8,4), 256, 0, stream>>>(yTb, ow, ob, y2, psum, qsum);
    k3b_stats<<<512, 256, 0, stream>>>(psum, qsum, meanA, invA);
    k4_final<<<2048, 256, 0, stream>>>(x, meanA, invA, gamma, beta, scale, out);
}

// Round 9
// 102.236 us; speedup vs baseline: 1.3815x; 1.3337x over previous
//
#include <hip/hip_runtime.h>
#include <hip/hip_bf16.h>
#include <math.h>

#define NPIX 4096   // H*W
#define CIN  512
#define DD   64
#define BB   4
#define NCHUNK 8    // KV chunks for flash-decode split (chunk = 512)

using f32x4  = __attribute__((ext_vector_type(4))) float;
using bf16x8 = __attribute__((ext_vector_type(8))) short;
using u16x4  = __attribute__((ext_vector_type(4))) unsigned short;

__device__ __forceinline__ unsigned short f2bf(float f){
    union { __hip_bfloat16 h; unsigned short u; } v;
    v.h = __float2bfloat16(f);            // RNE
    return v.u;
}

__device__ __forceinline__ unsigned pk2(float a, float b){
    union { __hip_bfloat162 h; unsigned u; } v;
    v.h = __float22bfloat162_rn(make_float2(a, b));   // v_cvt_pk_bf16_f32
    return v.u;
}

__device__ __forceinline__ bf16x8 cvt8(float4 a, float4 b){
    union { unsigned u[4]; bf16x8 v; } r;
    r.u[0] = pk2(a.x, a.y); r.u[1] = pk2(a.z, a.w);
    r.u[2] = pk2(b.x, b.y); r.u[3] = pk2(b.z, b.w);
    return r.v;
}

// ---------------------------------------------------------------------------
// Kernel 0: transpose+convert  x [B][C][N] f32  ->  xT [B][N][C] bf16.
// grid (64 n-tiles, 8 c-tiles, 4 b), block 256.  LDS tile transpose.
// ---------------------------------------------------------------------------
__global__ __launch_bounds__(256) void k0_xt(
    const float* __restrict__ x, unsigned short* __restrict__ xT)
{
    const int n0 = blockIdx.x * 64;
    const int c0 = blockIdx.y * 64;
    const int b  = blockIdx.z;
    const int tid = threadIdx.x;
    __shared__ __align__(16) unsigned short T[64*72];

    {   // load 64(k) x 64(n) fp32 coalesced, convert, store [k][n] bf16
        const int kr = tid >> 2, ns = (tid & 3) * 16;
        const float* xp = x + ((size_t)b*CIN + c0 + kr)*NPIX + n0 + ns;
        float4 a0 = *reinterpret_cast<const float4*>(xp);
        float4 a1 = *reinterpret_cast<const float4*>(xp + 4);
        float4 a2 = *reinterpret_cast<const float4*>(xp + 8);
        float4 a3 = *reinterpret_cast<const float4*>(xp + 12);
        *reinterpret_cast<bf16x8*>(&T[kr*72 + ns])     = cvt8(a0, a1);
        *reinterpret_cast<bf16x8*>(&T[kr*72 + ns + 8]) = cvt8(a2, a3);
    }
    __syncthreads();
    {   // read transposed, write xT rows (k contiguous)
        const int nr = tid >> 2, ks = (tid & 3) * 16;
        unsigned short v[16];
        #pragma unroll
        for (int i=0;i<16;++i) v[i] = T[(ks+i)*72 + nr];
        unsigned short* dst = xT + ((size_t)b*NPIX + n0 + nr)*CIN + c0 + ks;
        *reinterpret_cast<bf16x8*>(dst)     = *reinterpret_cast<bf16x8*>(&v[0]);
        *reinterpret_cast<bf16x8*>(dst + 8) = *reinterpret_cast<bf16x8*>(&v[8]);
    }
}

// ---------------------------------------------------------------------------
// Kernel 1: fused theta/phi/g 1x1 conv via MFMA.  DIRECT global->LDS staging
// (r5 structure: no register-held prefetch — that inflated HBM writes 4x).
// grid (64 n-tiles, 3 kt, 4 b), block 256 (4 waves).
// ---------------------------------------------------------------------------
__global__ __launch_bounds__(256, 4) void k1_qkv(
    const unsigned short* __restrict__ xT,
    const float* __restrict__ tw, const float* __restrict__ tbv,
    const float* __restrict__ pw, const float* __restrict__ pbv,
    const float* __restrict__ gw, const float* __restrict__ gbv,
    unsigned short* __restrict__ thetaT, unsigned short* __restrict__ phiT,
    unsigned short* __restrict__ g_dn)
{
    const int n0 = blockIdx.x * 64;
    const int kt = blockIdx.y;
    const int b  = blockIdx.z;
    const int tid = threadIdx.x;
    const float* W  = (kt==0) ? tw  : (kt==1) ? pw  : gw;
    const float* Bv = (kt==0) ? tbv : (kt==1) ? pbv : gbv;

    const int wq   = tid >> 6;
    const int lane = tid & 63;
    const int lr   = lane & 15;
    const int lg   = lane >> 4;

    __shared__ __align__(16) short Wt[64*72];   // W tile [m][k] bf16 (pad 8)
    __shared__ __align__(16) short Xt[64*72];   // xT tile [n][k] bf16 (pad 8)

    f32x4 acc[4];
    #pragma unroll
    for (int jt=0;jt<4;++jt) acc[jt] = (f32x4){0.f,0.f,0.f,0.f};

    const int srow = tid >> 2;           // staging row 0..63
    const int skq  = (tid & 3) * 16;     // staging k seg

    for (int k0 = 0; k0 < CIN; k0 += 64) {
        __syncthreads();
        {   // stage W [64 m][64 k] fp32 -> bf16 ; xT [64 n][64 k] bf16 copy
            const float* wp = W + (size_t)srow*CIN + k0 + skq;
            float4 w0 = *reinterpret_cast<const float4*>(wp);
            float4 w1 = *reinterpret_cast<const float4*>(wp + 4);
            float4 w2 = *reinterpret_cast<const float4*>(wp + 8);
            float4 w3 = *reinterpret_cast<const float4*>(wp + 12);
            *reinterpret_cast<bf16x8*>(&Wt[srow*72 + skq])     = cvt8(w0, w1);
            *reinterpret_cast<bf16x8*>(&Wt[srow*72 + skq + 8]) = cvt8(w2, w3);
            const unsigned short* xp = xT + ((size_t)b*NPIX + n0 + srow)*CIN + k0 + skq;
            *reinterpret_cast<bf16x8*>(&Xt[srow*72 + skq]) =
                *reinterpret_cast<const bf16x8*>(xp);
            *reinterpret_cast<bf16x8*>(&Xt[srow*72 + skq + 8]) =
                *reinterpret_cast<const bf16x8*>(xp + 8);
        }
        __syncthreads();

        __builtin_amdgcn_s_setprio(1);
        #pragma unroll
        for (int dc=0;dc<2;++dc){
            bf16x8 af = *reinterpret_cast<const bf16x8*>(&Wt[(wq*16+lr)*72 + dc*32 + lg*8]);
            #pragma unroll
            for (int jt=0;jt<4;++jt){
                bf16x8 bf = *reinterpret_cast<const bf16x8*>(&Xt[(jt*16+lr)*72 + dc*32 + lg*8]);
                acc[jt] = __builtin_amdgcn_mfma_f32_16x16x32_bf16(af, bf, acc[jt], 0,0,0);
            }
        }
        __builtin_amdgcn_s_setprio(0);
    }

    // acc[jt][r] = out[m = wq*16+lg*4+r][n = n0+jt*16+lr]
    const int mb = wq*16 + lg*4;
    float bv[4];
    #pragma unroll
    for (int r=0;r<4;++r) bv[r] = Bv[mb+r];

    if (kt < 2){
        unsigned short* dst = (kt==0) ? thetaT : phiT;   // [b][n][d], d contig
        #pragma unroll
        for (int jt=0;jt<4;++jt){
            union { unsigned u[2]; u16x4 v; } o;
            o.u[0] = pk2(acc[jt][0]+bv[0], acc[jt][1]+bv[1]);
            o.u[1] = pk2(acc[jt][2]+bv[2], acc[jt][3]+bv[3]);
            *reinterpret_cast<u16x4*>(&dst[((size_t)b*NPIX + n0 + jt*16+lr)*DD + mb]) = o.v;
        }
    } else {
        #pragma unroll
        for (int jt=0;jt<4;++jt)
            #pragma unroll
            for (int r=0;r<4;++r)
                g_dn[((size_t)b*DD + mb+r)*NPIX + n0 + jt*16+lr] = f2bf(acc[jt][r]+bv[r]);
    }
}

// ---------------------------------------------------------------------------
// Kernel 2: MFMA flash attention, KV-chunked, no running max (|S| <~ 10;
// clamp 60 is inf-insurance).  DIRECT global->LDS staging (r5 structure).
// P stored bf16 row-major [q][j] stride 72; PV A-frag is a plain b128 read.
// l via ones-B-fragment MFMA.
// ---------------------------------------------------------------------------
__global__ __launch_bounds__(256, 4) void k2_attn(
    const unsigned short* __restrict__ thetaT,
    const unsigned short* __restrict__ phiT,
    const unsigned short* __restrict__ g_dn,
    float* __restrict__ pY, float* __restrict__ pL)
{
    const int i0 = blockIdx.x * 64;
    const int ch = blockIdx.y;
    const int b  = blockIdx.z;
    const int tid  = threadIdx.x;
    const int wq   = tid >> 6;        // wave 0..3 -> q strip
    const int lane = tid & 63;
    const int lr   = lane & 15;       // row/col-in-16
    const int lg   = lane >> 4;       // k-group 0..3

    __shared__ __align__(16) short Kt[64*72];      // phiT tile [j][d] bf16 (pad 8)
    __shared__ __align__(16) short Gt[64*72];      // g tile [d][j] bf16 (pad 8)
    __shared__ __align__(16) short Pb[4*16*72];    // per-wave P [q][j] bf16, stride 72
    short* Pw = &Pb[wq*16*72];

    // Q fragments: rows i0+wq*16+lr, k = lg*8..+7 (+32)
    bf16x8 qf[2];
    {
        const unsigned short* qp = thetaT + ((size_t)b*NPIX + i0 + wq*16 + lr)*DD + lg*8;
        qf[0] = *reinterpret_cast<const bf16x8*>(qp);
        qf[1] = *reinterpret_cast<const bf16x8*>(qp + 32);
    }
    const bf16x8 onesf = { (short)0x3F80,(short)0x3F80,(short)0x3F80,(short)0x3F80,
                           (short)0x3F80,(short)0x3F80,(short)0x3F80,(short)0x3F80 };

    f32x4 yacc[4], lacc;
    #pragma unroll
    for (int dt=0;dt<4;++dt) yacc[dt] = (f32x4){0.f,0.f,0.f,0.f};
    lacc = (f32x4){0.f,0.f,0.f,0.f};

    const unsigned short* phb = phiT + (size_t)b*NPIX*DD;
    const unsigned short* gb  = g_dn + (size_t)b*DD*NPIX;

    const int jbeg = ch * (NPIX / NCHUNK);
    const int jend = jbeg + (NPIX / NCHUNK);

    const int srow = tid >> 3;          // 0..31 (two row passes: +0, +32)
    const int scb  = (tid & 7) * 8;     // bf16 col seg

    for (int j0 = jbeg; j0 < jend; j0 += 64) {
        __syncthreads();                          // prev-tile reads of Kt/Gt done
        *reinterpret_cast<float4*>(&Kt[srow*72 + scb]) =
            *reinterpret_cast<const float4*>(&phb[(size_t)(j0+srow)*DD + scb]);
        *reinterpret_cast<float4*>(&Kt[(srow+32)*72 + scb]) =
            *reinterpret_cast<const float4*>(&phb[(size_t)(j0+srow+32)*DD + scb]);
        *reinterpret_cast<float4*>(&Gt[srow*72 + scb]) =
            *reinterpret_cast<const float4*>(&gb[(size_t)srow*NPIX + j0 + scb]);
        *reinterpret_cast<float4*>(&Gt[(srow+32)*72 + scb]) =
            *reinterpret_cast<const float4*>(&gb[(size_t)(srow+32)*NPIX + j0 + scb]);
        __syncthreads();

        // ---- S strip: 16q x 64j in 4 accumulators ----
        f32x4 s[4];
        #pragma unroll
        for (int jt=0;jt<4;++jt) s[jt] = (f32x4){0.f,0.f,0.f,0.f};
        __builtin_amdgcn_s_setprio(1);
        #pragma unroll
        for (int dc=0;dc<2;++dc){
            #pragma unroll
            for (int jt=0;jt<4;++jt){
                bf16x8 bf = *reinterpret_cast<const bf16x8*>(&Kt[(jt*16+lr)*72 + dc*32 + lg*8]);
                s[jt] = __builtin_amdgcn_mfma_f32_16x16x32_bf16(qf[dc], bf, s[jt], 0,0,0);
            }
        }
        __builtin_amdgcn_s_setprio(0);

        // ---- p = exp(S) -> bf16 P[q][j] (acc: q=lg*4+r, j=jt*16+lr) ----
        #pragma unroll
        for (int jt=0;jt<4;++jt)
            #pragma unroll
            for (int r=0;r<4;++r){
                float p = __expf(fminf(s[jt][r], 60.f));
                Pw[(lg*4+r)*72 + jt*16 + lr] = (short)f2bf(p);
            }
        // same-wave write->read: compiler inserts lgkmcnt waits

        // ---- PV: yacc[q][d] += P . g ; lacc[q] += P . 1 ----
        __builtin_amdgcn_s_setprio(1);
        #pragma unroll
        for (int jc=0;jc<2;++jc){
            bf16x8 af = *reinterpret_cast<const bf16x8*>(&Pw[lr*72 + jc*32 + lg*8]);
            #pragma unroll
            for (int dt=0;dt<4;++dt){
                bf16x8 gf = *reinterpret_cast<const bf16x8*>(&Gt[(dt*16+lr)*72 + jc*32 + lg*8]);
                yacc[dt] = __builtin_amdgcn_mfma_f32_16x16x32_bf16(af, gf, yacc[dt], 0,0,0);
            }
            lacc = __builtin_amdgcn_mfma_f32_16x16x32_bf16(af, onesf, lacc, 0,0,0);
        }
        __builtin_amdgcn_s_setprio(0);
    }

    // ---- epilogue: store UNNORMALIZED partial + l ----
    float* py = pY + (((size_t)b*NCHUNK + ch)*NPIX + i0 + wq*16)*DD;
    #pragma unroll
    for (int r=0;r<4;++r){
        #pragma unroll
        for (int dt=0;dt<4;++dt)
            py[(size_t)(lg*4+r)*DD + dt*16 + lr] = yacc[dt][r];
    }
    if (lr == 0){                                  // lacc cols all equal l[q]
        const size_t base = ((size_t)b*NCHUNK + ch)*NPIX + i0 + wq*16;
        #pragma unroll
        for (int r=0;r<4;++r)
            pL[base + lg*4+r] = lacc[r];
    }
}

// ---------------------------------------------------------------------------
// Kernel 2c: combine partials (plain sums), emit bf16 yT [B][N][D].
// ---------------------------------------------------------------------------
__global__ __launch_bounds__(256) void k2c_combine(
    const float* __restrict__ pY, const float* __restrict__ pL,
    unsigned short* __restrict__ yTb)
{
    const int gid = blockIdx.x*256 + threadIdx.x;   // B*N*DD total
    const int d  = gid & (DD-1);
    const int qn = gid >> 6;          // b*NPIX + i
    const int b  = qn >> 12;
    const int i  = qn & (NPIX-1);

    float lsum = 0.f, y = 0.f;
    #pragma unroll
    for (int c=0;c<NCHUNK;++c){
        lsum += pL[((size_t)b*NCHUNK + c)*NPIX + i];
        y    += pY[(((size_t)b*NCHUNK + c)*NPIX + i)*DD + d];
    }
    yTb[(size_t)qn*DD + d] = f2bf(y / lsum);
}

// ---------------------------------------------------------------------------
// Kernel 3: out conv via MFMA + FUSED deterministic BN partial stats.
// grid (64 n-tiles, 8 c-tiles, 4 b), block 256.
// partial sums: psum/qsum [512 c][256 slot], slot = b*64 + n-tile.
// ---------------------------------------------------------------------------
__global__ __launch_bounds__(256) void k3_out(
    const unsigned short* __restrict__ yTb, const float* __restrict__ ow,
    const float* __restrict__ ob, float* __restrict__ y2,
    float* __restrict__ psum, float* __restrict__ qsum)
{
    const int n0 = blockIdx.x * 64;
    const int c0 = blockIdx.y * 64;
    const int b  = blockIdx.z;
    const int tid = threadIdx.x;
    const int wq   = tid >> 6;
    const int lane = tid & 63;
    const int lr   = lane & 15;
    const int lg   = lane >> 4;

    __shared__ __align__(16) short Ot[64*72];
    __shared__ __align__(16) short Yt[64*72];

    {   // stage ow [64 c][64 d] fp32 -> bf16 ; yTb [64 n][64 d] bf16
        const int srow = tid >> 2, skq = (tid & 3) * 16;
        const float* wp = ow + (size_t)(c0+srow)*DD + skq;
        float4 w0 = *reinterpret_cast<const float4*>(wp);
        float4 w1 = *reinterpret_cast<const float4*>(wp + 4);
        float4 w2 = *reinterpret_cast<const float4*>(wp + 8);
        float4 w3 = *reinterpret_cast<const float4*>(wp + 12);
        *reinterpret_cast<bf16x8*>(&Ot[srow*72 + skq])     = cvt8(w0, w1);
        *reinterpret_cast<bf16x8*>(&Ot[srow*72 + skq + 8]) = cvt8(w2, w3);
        const unsigned short* yp = yTb + ((size_t)b*NPIX + n0 + srow)*DD + skq;
        *reinterpret_cast<bf16x8*>(&Yt[srow*72 + skq]) =
            *reinterpret_cast<const bf16x8*>(yp);
        *reinterpret_cast<bf16x8*>(&Yt[srow*72 + skq + 8]) =
            *reinterpret_cast<const bf16x8*>(yp + 8);
    }
    __syncthreads();

    f32x4 acc[4];
    #pragma unroll
    for (int jt=0;jt<4;++jt) acc[jt] = (f32x4){0.f,0.f,0.f,0.f};
    #pragma unroll
    for (int dc=0;dc<2;++dc){
        bf16x8 af = *reinterpret_cast<const bf16x8*>(&Ot[(wq*16+lr)*72 + dc*32 + lg*8]);
        #pragma unroll
        for (int jt=0;jt<4;++jt){
            bf16x8 bf = *reinterpret_cast<const bf16x8*>(&Yt[(jt*16+lr)*72 + dc*32 + lg*8]);
            acc[jt] = __builtin_amdgcn_mfma_f32_16x16x32_bf16(af, bf, acc[jt], 0,0,0);
        }
    }

    const int cb = c0 + wq*16 + lg*4;
    float bv[4];
    #pragma unroll
    for (int r=0;r<4;++r) bv[r] = ob[cb+r];

    float sr[4] = {0,0,0,0}, qr[4] = {0,0,0,0};
    #pragma unroll
    for (int jt=0;jt<4;++jt)
        #pragma unroll
        for (int r=0;r<4;++r){
            float v = acc[jt][r] + bv[r];
            y2[((size_t)b*CIN + cb+r)*NPIX + n0 + jt*16+lr] = v;
            sr[r] += v; qr[r] += v*v;
        }
    // reduce over lr (lane bits 0..3) -> per-channel partials for 64 n
    #pragma unroll
    for (int off=1; off<16; off<<=1)
        #pragma unroll
        for (int r=0;r<4;++r){
            sr[r] += __shfl_xor(sr[r], off);
            qr[r] += __shfl_xor(qr[r], off);
        }
    if (lr == 0){
        const int slot = b*64 + blockIdx.x;
        #pragma unroll
        for (int r=0;r<4;++r){
            psum[(size_t)(cb+r)*256 + slot] = sr[r];
            qsum[(size_t)(cb+r)*256 + slot] = qr[r];
        }
    }
}

// ---------------------------------------------------------------------------
// Kernel 3b: reduce [512][256] partials -> mean/inv (deterministic tree).
// ---------------------------------------------------------------------------
__global__ __launch_bounds__(256) void k3b_stats(
    const float* __restrict__ psum, const float* __restrict__ qsum,
    float* __restrict__ meanA, float* __restrict__ invA)
{
    const int c = blockIdx.x;
    const int tid = threadIdx.x;
    float s = psum[(size_t)c*256 + tid];
    float q = qsum[(size_t)c*256 + tid];
    __shared__ float rs[256], rq[256];
    rs[tid]=s; rq[tid]=q; __syncthreads();
    for (int off=128; off; off>>=1){
        if (tid<off){ rs[tid]+=rs[tid+off]; rq[tid]+=rq[tid+off]; }
        __syncthreads();
    }
    if (tid==0){
        const float n = (float)(BB*NPIX);
        float mm = rs[0] / n;
        float v = rq[0] / n - mm*mm;
        meanA[c]=mm; invA[c]=rsqrtf(v + 1e-5f);
    }
}

// ---------------------------------------------------------------------------
// Kernel 4: in-place BN apply + residual.
// ---------------------------------------------------------------------------
__global__ __launch_bounds__(256) void k4_final(
    const float* __restrict__ x,
    const float* __restrict__ meanA, const float* __restrict__ invA,
    const float* __restrict__ gamma, const float* __restrict__ beta,
    const float* __restrict__ scale, float* out /*aliases y2*/)
{
    const float sc = scale[0];
    const int total4 = BB*CIN*NPIX/4;
    for (int i4 = blockIdx.x*blockDim.x + threadIdx.x; i4 < total4;
         i4 += gridDim.x*blockDim.x){
        int c = (i4 >> 10) & (CIN-1);
        float4 xv = reinterpret_cast<const float4*>(x)[i4];
        float4 yv = reinterpret_cast<float4*>(out)[i4];
        float mm = meanA[c], iv = invA[c], g = gamma[c], bt = beta[c];
        float4 o;
        o.x = xv.x + sc*(g*(yv.x-mm)*iv + bt);
        o.y = xv.y + sc*(g*(yv.y-mm)*iv + bt);
        o.z = xv.z + sc*(g*(yv.z-mm)*iv + bt);
        o.w = xv.w + sc*(g*(yv.w-mm)*iv + bt);
        reinterpret_cast<float4*>(out)[i4] = o;
    }
}

// ---------------------------------------------------------------------------
extern "C" void kernel_launch(void* const* d_in, const int* in_sizes, int n_in,
                              void* d_out, int out_size, void* d_ws, size_t ws_size,
                              hipStream_t stream)
{
    const float* x     = (const float*)d_in[0];
    const float* tw    = (const float*)d_in[1];
    const float* tbv   = (const float*)d_in[2];
    const float* pw    = (const float*)d_in[3];
    const float* pbv   = (const float*)d_in[4];
    const float* gw    = (const float*)d_in[5];
    const float* gbv   = (const float*)d_in[6];
    const float* ow    = (const float*)d_in[7];
    const float* ob    = (const float*)d_in[8];
    const float* gamma = (const float*)d_in[9];
    const float* beta  = (const float*)d_in[10];
    const float* scale = (const float*)d_in[11];
    float* out = (float*)d_out;

    char* wsb = (char*)d_ws;
    unsigned short* thetaT = (unsigned short*)(wsb);             // 2 MB
    unsigned short* phiT   = (unsigned short*)(wsb + 2097152);   // 2 MB
    unsigned short* g_dn   = (unsigned short*)(wsb + 4194304);   // 2 MB
    unsigned short* yTb    = (unsigned short*)(wsb + 6291456);   // 2 MB
    float*          pL     = (float*)(wsb + 8388608);            // 512 KB
    float*          psum   = (float*)(wsb + 8912896);            // 512 KB
    float*          qsum   = (float*)(wsb + 9437184);            // 512 KB
    float*          meanA  = (float*)(wsb + 9961472);
    float*          invA   = (float*)(wsb + 9963520);

    // d_out (33.5 MB) is time-shared scratch:
    //   phase A: xT [B][N][C] bf16 (16.8 MB)  -- k0 writes, k1 reads
    //   phase B: pY [B][NCHUNK][N][D] f32 (33.5 MB) -- k2 writes, k2c reads
    //   phase C: y2 [B][C][N] f32 -- k3 writes, k4 reads/writes final
    unsigned short* xT = (unsigned short*)d_out;
    float* pY = out;
    float* y2 = out;

    k0_xt  <<<dim3(64,8,4), 256, 0, stream>>>(x, xT);
    k1_qkv <<<dim3(64,3,4), 256, 0, stream>>>(xT, tw, tbv, pw, pbv, gw, gbv,
                                              thetaT, phiT, g_dn);
    k2_attn<<<dim3(64,NCHUNK,4), 256, 0, stream>>>(thetaT, phiT, g_dn, pY, pL);
    k2c_combine<<<4096, 256, 0, stream>>>(pY, pL, yTb);
    k3_out <<<dim3(64,8,4), 256, 0, stream>>>(yTb, ow, ob, y2, psum, qsum);
    k3b_stats<<<512, 256, 0, stream>>>(psum, qsum, meanA, invA);
    k4_final<<<2048, 256, 0, stream>>>(x, meanA, invA, gamma, beta, scale, out);
}

// Round 10
// 96.714 us; speedup vs baseline: 1.4603x; 1.0571x over previous
//
#include <hip/hip_runtime.h>
#include <hip/hip_bf16.h>
#include <math.h>

#define NPIX 4096   // H*W
#define CIN  512
#define DD   64
#define BB   4
#define NCHUNK 8    // KV chunks for flash-decode split (chunk = 512)

using f32x4  = __attribute__((ext_vector_type(4))) float;
using bf16x8 = __attribute__((ext_vector_type(8))) short;
using u16x4  = __attribute__((ext_vector_type(4))) unsigned short;

__device__ __forceinline__ unsigned short f2bf(float f){
    union { __hip_bfloat16 h; unsigned short u; } v;
    v.h = __float2bfloat16(f);            // RNE
    return v.u;
}

__device__ __forceinline__ float bf2f(unsigned short u){
    union { unsigned u; float f; } v; v.u = ((unsigned)u) << 16; return v.f;
}

__device__ __forceinline__ unsigned pk2(float a, float b){
    union { __hip_bfloat162 h; unsigned u; } v;
    v.h = __float22bfloat162_rn(make_float2(a, b));   // v_cvt_pk_bf16_f32
    return v.u;
}

__device__ __forceinline__ bf16x8 cvt8(float4 a, float4 b){
    union { unsigned u[4]; bf16x8 v; } r;
    r.u[0] = pk2(a.x, a.y); r.u[1] = pk2(a.z, a.w);
    r.u[2] = pk2(b.x, b.y); r.u[3] = pk2(b.z, b.w);
    return r.v;
}

// ---------------------------------------------------------------------------
// Kernel 0: transpose+convert  x [B][C][N] f32  ->  xT [B][N][C] bf16.
// grid (64 n-tiles, 8 c-tiles, 4 b), block 256.  LDS tile transpose.
// ---------------------------------------------------------------------------
__global__ __launch_bounds__(256) void k0_xt(
    const float* __restrict__ x, unsigned short* __restrict__ xT)
{
    const int n0 = blockIdx.x * 64;
    const int c0 = blockIdx.y * 64;
    const int b  = blockIdx.z;
    const int tid = threadIdx.x;
    __shared__ __align__(16) unsigned short T[64*72];

    {   // load 64(k) x 64(n) fp32 coalesced, convert, store [k][n] bf16
        const int kr = tid >> 2, ns = (tid & 3) * 16;
        const float* xp = x + ((size_t)b*CIN + c0 + kr)*NPIX + n0 + ns;
        float4 a0 = *reinterpret_cast<const float4*>(xp);
        float4 a1 = *reinterpret_cast<const float4*>(xp + 4);
        float4 a2 = *reinterpret_cast<const float4*>(xp + 8);
        float4 a3 = *reinterpret_cast<const float4*>(xp + 12);
        *reinterpret_cast<bf16x8*>(&T[kr*72 + ns])     = cvt8(a0, a1);
        *reinterpret_cast<bf16x8*>(&T[kr*72 + ns + 8]) = cvt8(a2, a3);
    }
    __syncthreads();
    {   // read transposed, write xT rows (k contiguous)
        const int nr = tid >> 2, ks = (tid & 3) * 16;
        unsigned short v[16];
        #pragma unroll
        for (int i=0;i<16;++i) v[i] = T[(ks+i)*72 + nr];
        unsigned short* dst = xT + ((size_t)b*NPIX + n0 + nr)*CIN + c0 + ks;
        *reinterpret_cast<bf16x8*>(dst)     = *reinterpret_cast<bf16x8*>(&v[0]);
        *reinterpret_cast<bf16x8*>(dst + 8) = *reinterpret_cast<bf16x8*>(&v[8]);
    }
}

// ---------------------------------------------------------------------------
// Kernel 1: fused theta/phi/g 1x1 conv via MFMA.  Direct global->LDS staging.
// theta (kt==0) is PRE-SCALED by log2(e) so k2 can use exp2 directly
// (S is linear in theta; softmax result unchanged).
// grid (64 n-tiles, 3 kt, 4 b), block 256 (4 waves).
// ---------------------------------------------------------------------------
__global__ __launch_bounds__(256, 4) void k1_qkv(
    const unsigned short* __restrict__ xT,
    const float* __restrict__ tw, const float* __restrict__ tbv,
    const float* __restrict__ pw, const float* __restrict__ pbv,
    const float* __restrict__ gw, const float* __restrict__ gbv,
    unsigned short* __restrict__ thetaT, unsigned short* __restrict__ phiT,
    unsigned short* __restrict__ g_dn)
{
    const int n0 = blockIdx.x * 64;
    const int kt = blockIdx.y;
    const int b  = blockIdx.z;
    const int tid = threadIdx.x;
    const float* W  = (kt==0) ? tw  : (kt==1) ? pw  : gw;
    const float* Bv = (kt==0) ? tbv : (kt==1) ? pbv : gbv;
    const float wsc = (kt==0) ? 1.4426950408889634f : 1.0f;   // log2(e)

    const int wq   = tid >> 6;
    const int lane = tid & 63;
    const int lr   = lane & 15;
    const int lg   = lane >> 4;

    __shared__ __align__(16) short Wt[64*72];   // W tile [m][k] bf16 (pad 8)
    __shared__ __align__(16) short Xt[64*72];   // xT tile [n][k] bf16 (pad 8)

    f32x4 acc[4];
    #pragma unroll
    for (int jt=0;jt<4;++jt) acc[jt] = (f32x4){0.f,0.f,0.f,0.f};

    const int srow = tid >> 2;           // staging row 0..63
    const int skq  = (tid & 3) * 16;     // staging k seg

    for (int k0 = 0; k0 < CIN; k0 += 64) {
        __syncthreads();
        {   // stage W [64 m][64 k] fp32 -> bf16 (scaled) ; xT bf16 copy
            const float* wp = W + (size_t)srow*CIN + k0 + skq;
            float4 w0 = *reinterpret_cast<const float4*>(wp);
            float4 w1 = *reinterpret_cast<const float4*>(wp + 4);
            float4 w2 = *reinterpret_cast<const float4*>(wp + 8);
            float4 w3 = *reinterpret_cast<const float4*>(wp + 12);
            w0.x*=wsc; w0.y*=wsc; w0.z*=wsc; w0.w*=wsc;
            w1.x*=wsc; w1.y*=wsc; w1.z*=wsc; w1.w*=wsc;
            w2.x*=wsc; w2.y*=wsc; w2.z*=wsc; w2.w*=wsc;
            w3.x*=wsc; w3.y*=wsc; w3.z*=wsc; w3.w*=wsc;
            *reinterpret_cast<bf16x8*>(&Wt[srow*72 + skq])     = cvt8(w0, w1);
            *reinterpret_cast<bf16x8*>(&Wt[srow*72 + skq + 8]) = cvt8(w2, w3);
            const unsigned short* xp = xT + ((size_t)b*NPIX + n0 + srow)*CIN + k0 + skq;
            *reinterpret_cast<bf16x8*>(&Xt[srow*72 + skq]) =
                *reinterpret_cast<const bf16x8*>(xp);
            *reinterpret_cast<bf16x8*>(&Xt[srow*72 + skq + 8]) =
                *reinterpret_cast<const bf16x8*>(xp + 8);
        }
        __syncthreads();

        __builtin_amdgcn_s_setprio(1);
        #pragma unroll
        for (int dc=0;dc<2;++dc){
            bf16x8 af = *reinterpret_cast<const bf16x8*>(&Wt[(wq*16+lr)*72 + dc*32 + lg*8]);
            #pragma unroll
            for (int jt=0;jt<4;++jt){
                bf16x8 bf = *reinterpret_cast<const bf16x8*>(&Xt[(jt*16+lr)*72 + dc*32 + lg*8]);
                acc[jt] = __builtin_amdgcn_mfma_f32_16x16x32_bf16(af, bf, acc[jt], 0,0,0);
            }
        }
        __builtin_amdgcn_s_setprio(0);
    }

    // acc[jt][r] = out[m = wq*16+lg*4+r][n = n0+jt*16+lr]
    const int mb = wq*16 + lg*4;
    float bv[4];
    #pragma unroll
    for (int r=0;r<4;++r) bv[r] = Bv[mb+r] * wsc;

    if (kt < 2){
        unsigned short* dst = (kt==0) ? thetaT : phiT;   // [b][n][d], d contig
        #pragma unroll
        for (int jt=0;jt<4;++jt){
            union { unsigned u[2]; u16x4 v; } o;
            o.u[0] = pk2(acc[jt][0]+bv[0], acc[jt][1]+bv[1]);
            o.u[1] = pk2(acc[jt][2]+bv[2], acc[jt][3]+bv[3]);
            *reinterpret_cast<u16x4*>(&dst[((size_t)b*NPIX + n0 + jt*16+lr)*DD + mb]) = o.v;
        }
    } else {
        #pragma unroll
        for (int jt=0;jt<4;++jt)
            #pragma unroll
            for (int r=0;r<4;++r)
                g_dn[((size_t)b*DD + mb+r)*NPIX + n0 + jt*16+lr] = f2bf(acc[jt][r]+bv[r]);
    }
}

// ---------------------------------------------------------------------------
// Kernel 2: MFMA flash attention, KV-chunked, no running max.
// TWO Q-strips per wave (block covers 128 q rows): each Kt/Gt fragment read
// feeds 2 MFMAs -> DS-read pressure per q-row cut ~1.6x.
// theta pre-scaled by log2e -> p = exp2(S).  pY partials stored bf16.
// grid (32 q-tiles, NCHUNK, 4 b), block 256 (4 waves).
// ---------------------------------------------------------------------------
__global__ __launch_bounds__(256, 4) void k2_attn(
    const unsigned short* __restrict__ thetaT,
    const unsigned short* __restrict__ phiT,
    const unsigned short* __restrict__ g_dn,
    unsigned short* __restrict__ pY, float* __restrict__ pL)
{
    const int i0 = blockIdx.x * 128;
    const int ch = blockIdx.y;
    const int b  = blockIdx.z;
    const int tid  = threadIdx.x;
    const int wq   = tid >> 6;        // wave 0..3
    const int lane = tid & 63;
    const int lr   = lane & 15;       // row/col-in-16
    const int lg   = lane >> 4;       // k-group 0..3

    __shared__ __align__(16) short Kt[64*72];      // phiT tile [j][d] bf16 (pad 8)
    __shared__ __align__(16) short Gt[64*72];      // g tile [d][j] bf16 (pad 8)
    __shared__ __align__(16) short Pb[4*32*72];    // per-wave P [2 strips x 16 q][j]
    short* Pw = &Pb[wq*32*72];

    // Q fragments, strip0: rows i0+wq*16+lr ; strip1: +64
    bf16x8 qf0[2], qf1[2];
    {
        const unsigned short* qp0 = thetaT + ((size_t)b*NPIX + i0 + wq*16 + lr)*DD + lg*8;
        qf0[0] = *reinterpret_cast<const bf16x8*>(qp0);
        qf0[1] = *reinterpret_cast<const bf16x8*>(qp0 + 32);
        const unsigned short* qp1 = qp0 + (size_t)64*DD;
        qf1[0] = *reinterpret_cast<const bf16x8*>(qp1);
        qf1[1] = *reinterpret_cast<const bf16x8*>(qp1 + 32);
    }
    const bf16x8 onesf = { (short)0x3F80,(short)0x3F80,(short)0x3F80,(short)0x3F80,
                           (short)0x3F80,(short)0x3F80,(short)0x3F80,(short)0x3F80 };

    f32x4 yacc0[4], yacc1[4], lacc0, lacc1;
    #pragma unroll
    for (int dt=0;dt<4;++dt){
        yacc0[dt] = (f32x4){0.f,0.f,0.f,0.f};
        yacc1[dt] = (f32x4){0.f,0.f,0.f,0.f};
    }
    lacc0 = (f32x4){0.f,0.f,0.f,0.f};
    lacc1 = (f32x4){0.f,0.f,0.f,0.f};

    const unsigned short* phb = phiT + (size_t)b*NPIX*DD;
    const unsigned short* gb  = g_dn + (size_t)b*DD*NPIX;

    const int jbeg = ch * (NPIX / NCHUNK);
    const int jend = jbeg + (NPIX / NCHUNK);

    const int srow = tid >> 3;          // 0..31 (two row passes: +0, +32)
    const int scb  = (tid & 7) * 8;     // bf16 col seg

    for (int j0 = jbeg; j0 < jend; j0 += 64) {
        __syncthreads();                          // prev-tile reads of Kt/Gt done
        *reinterpret_cast<float4*>(&Kt[srow*72 + scb]) =
            *reinterpret_cast<const float4*>(&phb[(size_t)(j0+srow)*DD + scb]);
        *reinterpret_cast<float4*>(&Kt[(srow+32)*72 + scb]) =
            *reinterpret_cast<const float4*>(&phb[(size_t)(j0+srow+32)*DD + scb]);
        *reinterpret_cast<float4*>(&Gt[srow*72 + scb]) =
            *reinterpret_cast<const float4*>(&gb[(size_t)srow*NPIX + j0 + scb]);
        *reinterpret_cast<float4*>(&Gt[(srow+32)*72 + scb]) =
            *reinterpret_cast<const float4*>(&gb[(size_t)(srow+32)*NPIX + j0 + scb]);
        __syncthreads();

        // ---- S: 2 strips x 16q x 64j ; each Kt fragment feeds both strips ----
        f32x4 s0[4], s1[4];
        #pragma unroll
        for (int jt=0;jt<4;++jt){
            s0[jt] = (f32x4){0.f,0.f,0.f,0.f};
            s1[jt] = (f32x4){0.f,0.f,0.f,0.f};
        }
        __builtin_amdgcn_s_setprio(1);
        #pragma unroll
        for (int dc=0;dc<2;++dc){
            #pragma unroll
            for (int jt=0;jt<4;++jt){
                bf16x8 bf = *reinterpret_cast<const bf16x8*>(&Kt[(jt*16+lr)*72 + dc*32 + lg*8]);
                s0[jt] = __builtin_amdgcn_mfma_f32_16x16x32_bf16(qf0[dc], bf, s0[jt], 0,0,0);
                s1[jt] = __builtin_amdgcn_mfma_f32_16x16x32_bf16(qf1[dc], bf, s1[jt], 0,0,0);
            }
        }
        __builtin_amdgcn_s_setprio(0);

        // ---- p = exp2(S) -> bf16 P[strip*16+q][j] ----
        #pragma unroll
        for (int jt=0;jt<4;++jt)
            #pragma unroll
            for (int r=0;r<4;++r){
                Pw[(lg*4+r)*72      + jt*16 + lr] = (short)f2bf(exp2f(fminf(s0[jt][r], 86.f)));
                Pw[(16+lg*4+r)*72   + jt*16 + lr] = (short)f2bf(exp2f(fminf(s1[jt][r], 86.f)));
            }
        // same-wave write->read: compiler inserts lgkmcnt waits

        // ---- PV: each Gt fragment feeds both strips ----
        __builtin_amdgcn_s_setprio(1);
        #pragma unroll
        for (int jc=0;jc<2;++jc){
            bf16x8 af0 = *reinterpret_cast<const bf16x8*>(&Pw[lr*72      + jc*32 + lg*8]);
            bf16x8 af1 = *reinterpret_cast<const bf16x8*>(&Pw[(16+lr)*72 + jc*32 + lg*8]);
            #pragma unroll
            for (int dt=0;dt<4;++dt){
                bf16x8 gf = *reinterpret_cast<const bf16x8*>(&Gt[(dt*16+lr)*72 + jc*32 + lg*8]);
                yacc0[dt] = __builtin_amdgcn_mfma_f32_16x16x32_bf16(af0, gf, yacc0[dt], 0,0,0);
                yacc1[dt] = __builtin_amdgcn_mfma_f32_16x16x32_bf16(af1, gf, yacc1[dt], 0,0,0);
            }
            lacc0 = __builtin_amdgcn_mfma_f32_16x16x32_bf16(af0, onesf, lacc0, 0,0,0);
            lacc1 = __builtin_amdgcn_mfma_f32_16x16x32_bf16(af1, onesf, lacc1, 0,0,0);
        }
        __builtin_amdgcn_s_setprio(0);
    }

    // ---- epilogue: store UNNORMALIZED bf16 partials + l (both strips) ----
    {
        unsigned short* py0 = pY + (((size_t)b*NCHUNK + ch)*NPIX + i0 + wq*16)*DD;
        unsigned short* py1 = py0 + (size_t)64*DD;
        #pragma unroll
        for (int r=0;r<4;++r)
            #pragma unroll
            for (int dt=0;dt<4;++dt){
                py0[(size_t)(lg*4+r)*DD + dt*16 + lr] = f2bf(yacc0[dt][r]);
                py1[(size_t)(lg*4+r)*DD + dt*16 + lr] = f2bf(yacc1[dt][r]);
            }
        if (lr == 0){
            const size_t base = ((size_t)b*NCHUNK + ch)*NPIX + i0 + wq*16;
            #pragma unroll
            for (int r=0;r<4;++r){
                pL[base + lg*4+r]      = lacc0[r];
                pL[base + 64 + lg*4+r] = lacc1[r];
            }
        }
    }
}

// ---------------------------------------------------------------------------
// Kernel 2c: combine bf16 partials (plain sums), emit bf16 yT [B][N][D].
// Each thread handles 2 consecutive d (ushort2 loads).  grid 2048 x 256.
// ---------------------------------------------------------------------------
__global__ __launch_bounds__(256) void k2c_combine(
    const unsigned short* __restrict__ pY, const float* __restrict__ pL,
    unsigned short* __restrict__ yTb)
{
    const int gid = blockIdx.x*256 + threadIdx.x;   // B*N*DD/2 total
    const int d2 = gid & 31;          // d pair: d = d2*2
    const int qn = gid >> 5;          // b*NPIX + i
    const int b  = qn >> 12;
    const int i  = qn & (NPIX-1);

    float lsum = 0.f, y0 = 0.f, y1 = 0.f;
    #pragma unroll
    for (int c=0;c<NCHUNK;++c){
        lsum += pL[((size_t)b*NCHUNK + c)*NPIX + i];
        ushort2 v = *reinterpret_cast<const ushort2*>(
            &pY[(((size_t)b*NCHUNK + c)*NPIX + i)*DD + d2*2]);
        y0 += bf2f(v.x); y1 += bf2f(v.y);
    }
    float inv = 1.f / lsum;
    *reinterpret_cast<unsigned*>(&yTb[(size_t)qn*DD + d2*2]) = pk2(y0*inv, y1*inv);
}

// ---------------------------------------------------------------------------
// Kernel 3: out conv via MFMA + FUSED deterministic BN partial stats.
// grid (64 n-tiles, 8 c-tiles, 4 b), block 256.
// partial sums: psum/qsum [512 c][256 slot], slot = b*64 + n-tile.
// ---------------------------------------------------------------------------
__global__ __launch_bounds__(256) void k3_out(
    const unsigned short* __restrict__ yTb, const float* __restrict__ ow,
    const float* __restrict__ ob, float* __restrict__ y2,
    float* __restrict__ psum, float* __restrict__ qsum)
{
    const int n0 = blockIdx.x * 64;
    const int c0 = blockIdx.y * 64;
    const int b  = blockIdx.z;
    const int tid = threadIdx.x;
    const int wq   = tid >> 6;
    const int lane = tid & 63;
    const int lr   = lane & 15;
    const int lg   = lane >> 4;

    __shared__ __align__(16) short Ot[64*72];
    __shared__ __align__(16) short Yt[64*72];

    {   // stage ow [64 c][64 d] fp32 -> bf16 ; yTb [64 n][64 d] bf16
        const int srow = tid >> 2, skq = (tid & 3) * 16;
        const float* wp = ow + (size_t)(c0+srow)*DD + skq;
        float4 w0 = *reinterpret_cast<const float4*>(wp);
        float4 w1 = *reinterpret_cast<const float4*>(wp + 4);
        float4 w2 = *reinterpret_cast<const float4*>(wp + 8);
        float4 w3 = *reinterpret_cast<const float4*>(wp + 12);
        *reinterpret_cast<bf16x8*>(&Ot[srow*72 + skq])     = cvt8(w0, w1);
        *reinterpret_cast<bf16x8*>(&Ot[srow*72 + skq + 8]) = cvt8(w2, w3);
        const unsigned short* yp = yTb + ((size_t)b*NPIX + n0 + srow)*DD + skq;
        *reinterpret_cast<bf16x8*>(&Yt[srow*72 + skq]) =
            *reinterpret_cast<const bf16x8*>(yp);
        *reinterpret_cast<bf16x8*>(&Yt[srow*72 + skq + 8]) =
            *reinterpret_cast<const bf16x8*>(yp + 8);
    }
    __syncthreads();

    f32x4 acc[4];
    #pragma unroll
    for (int jt=0;jt<4;++jt) acc[jt] = (f32x4){0.f,0.f,0.f,0.f};
    #pragma unroll
    for (int dc=0;dc<2;++dc){
        bf16x8 af = *reinterpret_cast<const bf16x8*>(&Ot[(wq*16+lr)*72 + dc*32 + lg*8]);
        #pragma unroll
        for (int jt=0;jt<4;++jt){
            bf16x8 bf = *reinterpret_cast<const bf16x8*>(&Yt[(jt*16+lr)*72 + dc*32 + lg*8]);
            acc[jt] = __builtin_amdgcn_mfma_f32_16x16x32_bf16(af, bf, acc[jt], 0,0,0);
        }
    }

    const int cb = c0 + wq*16 + lg*4;
    float bv[4];
    #pragma unroll
    for (int r=0;r<4;++r) bv[r] = ob[cb+r];

    float sr[4] = {0,0,0,0}, qr[4] = {0,0,0,0};
    #pragma unroll
    for (int jt=0;jt<4;++jt)
        #pragma unroll
        for (int r=0;r<4;++r){
            float v = acc[jt][r] + bv[r];
            y2[((size_t)b*CIN + cb+r)*NPIX + n0 + jt*16+lr] = v;
            sr[r] += v; qr[r] += v*v;
        }
    // reduce over lr (lane bits 0..3) -> per-channel partials for 64 n
    #pragma unroll
    for (int off=1; off<16; off<<=1)
        #pragma unroll
        for (int r=0;r<4;++r){
            sr[r] += __shfl_xor(sr[r], off);
            qr[r] += __shfl_xor(qr[r], off);
        }
    if (lr == 0){
        const int slot = b*64 + blockIdx.x;
        #pragma unroll
        for (int r=0;r<4;++r){
            psum[(size_t)(cb+r)*256 + slot] = sr[r];
            qsum[(size_t)(cb+r)*256 + slot] = qr[r];
        }
    }
}

// ---------------------------------------------------------------------------
// Kernel 3b: reduce [512][256] partials -> mean/inv (deterministic tree).
// ---------------------------------------------------------------------------
__global__ __launch_bounds__(256) void k3b_stats(
    const float* __restrict__ psum, const float* __restrict__ qsum,
    float* __restrict__ meanA, float* __restrict__ invA)
{
    const int c = blockIdx.x;
    const int tid = threadIdx.x;
    float s = psum[(size_t)c*256 + tid];
    float q = qsum[(size_t)c*256 + tid];
    __shared__ float rs[256], rq[256];
    rs[tid]=s; rq[tid]=q; __syncthreads();
    for (int off=128; off; off>>=1){
        if (tid<off){ rs[tid]+=rs[tid+off]; rq[tid]+=rq[tid+off]; }
        __syncthreads();
    }
    if (tid==0){
        const float n = (float)(BB*NPIX);
        float mm = rs[0] / n;
        float v = rq[0] / n - mm*mm;
        meanA[c]=mm; invA[c]=rsqrtf(v + 1e-5f);
    }
}

// ---------------------------------------------------------------------------
// Kernel 4: in-place BN apply + residual.
// ---------------------------------------------------------------------------
__global__ __launch_bounds__(256) void k4_final(
    const float* __restrict__ x,
    const float* __restrict__ meanA, const float* __restrict__ invA,
    const float* __restrict__ gamma, const float* __restrict__ beta,
    const float* __restrict__ scale, float* out /*aliases y2*/)
{
    const float sc = scale[0];
    const int total4 = BB*CIN*NPIX/4;
    for (int i4 = blockIdx.x*blockDim.x + threadIdx.x; i4 < total4;
         i4 += gridDim.x*blockDim.x){
        int c = (i4 >> 10) & (CIN-1);
        float4 xv = reinterpret_cast<const float4*>(x)[i4];
        float4 yv = reinterpret_cast<float4*>(out)[i4];
        float mm = meanA[c], iv = invA[c], g = gamma[c], bt = beta[c];
        float4 o;
        o.x = xv.x + sc*(g*(yv.x-mm)*iv + bt);
        o.y = xv.y + sc*(g*(yv.y-mm)*iv + bt);
        o.z = xv.z + sc*(g*(yv.z-mm)*iv + bt);
        o.w = xv.w + sc*(g*(yv.w-mm)*iv + bt);
        reinterpret_cast<float4*>(out)[i4] = o;
    }
}

// ---------------------------------------------------------------------------
extern "C" void kernel_launch(void* const* d_in, const int* in_sizes, int n_in,
                              void* d_out, int out_size, void* d_ws, size_t ws_size,
                              hipStream_t stream)
{
    const float* x     = (const float*)d_in[0];
    const float* tw    = (const float*)d_in[1];
    const float* tbv   = (const float*)d_in[2];
    const float* pw    = (const float*)d_in[3];
    const float* pbv   = (const float*)d_in[4];
    const float* gw    = (const float*)d_in[5];
    const float* gbv   = (const float*)d_in[6];
    const float* ow    = (const float*)d_in[7];
    const float* ob    = (const float*)d_in[8];
    const float* gamma = (const float*)d_in[9];
    const float* beta  = (const float*)d_in[10];
    const float* scale = (const float*)d_in[11];
    float* out = (float*)d_out;

    char* wsb = (char*)d_ws;
    unsigned short* thetaT = (unsigned short*)(wsb);             // 2 MB
    unsigned short* phiT   = (unsigned short*)(wsb + 2097152);   // 2 MB
    unsigned short* g_dn   = (unsigned short*)(wsb + 4194304);   // 2 MB
    unsigned short* yTb    = (unsigned short*)(wsb + 6291456);   // 2 MB
    float*          pL     = (float*)(wsb + 8388608);            // 512 KB
    float*          psum   = (float*)(wsb + 8912896);            // 512 KB
    float*          qsum   = (float*)(wsb + 9437184);            // 512 KB
    float*          meanA  = (float*)(wsb + 9961472);
    float*          invA   = (float*)(wsb + 9963520);

    // d_out (33.5 MB) is time-shared scratch:
    //   phase A: xT [B][N][C] bf16 (16.8 MB)  -- k0 writes, k1 reads
    //   phase B: pY [B][NCHUNK][N][D] bf16 (16.8 MB) -- k2 writes, k2c reads
    //   phase C: y2 [B][C][N] f32 -- k3 writes, k4 reads/writes final
    unsigned short* xT = (unsigned short*)d_out;
    unsigned short* pY = (unsigned short*)d_out;
    float* y2 = out;

    k0_xt  <<<dim3(64,8,4), 256, 0, stream>>>(x, xT);
    k1_qkv <<<dim3(64,3,4), 256, 0, stream>>>(xT, tw, tbv, pw, pbv, gw, gbv,
                                              thetaT, phiT, g_dn);
    k2_attn<<<dim3(32,NCHUNK,4), 256, 0, stream>>>(thetaT, phiT, g_dn, pY, pL);
    k2c_combine<<<2048, 256, 0, stream>>>(pY, pL, yTb);
    k3_out <<<dim3(64,8,4), 256, 0, stream>>>(yTb, ow, ob, y2, psum, qsum);
    k3b_stats<<<512, 256, 0, stream>>>(psum, qsum, meanA, invA);
    k4_final<<<2048, 256, 0, stream>>>(x, meanA, invA, gamma, beta, scale, out);
}